// Round 12
// baseline (7678.353 us; speedup 1.0000x reference)
//
#include <hip/hip_runtime.h>
#include <math.h>

#define D_    1024
#define B_    2
#define N_    512
#define SEG_  128
#define NSEG_ 4
#define NPT_  16
#define T_    272
#define NH_   16
#define HD_   64
#define W_    128
#define V_    32000

#define THETA_ 0.1f
#define ETA_   0.9f
#define PDEC_  0.99f
#define EPSN_  1e-6f
#define NB2_  32
#define FSTR_ 32

typedef __bf16 bf16x8 __attribute__((ext_vector_type(8)));
typedef float  f32x4  __attribute__((ext_vector_type(4)));

// ---------------- workspace layout (float offsets) ----------------
static const size_t XEMB = 0;
static const size_t OUTS = XEMB + (size_t)B_*N_*D_;
static const size_t PW1  = OUTS + (size_t)B_*N_*D_;
static const size_t PB1  = PW1  + (size_t)B_*D_*W_;
static const size_t PW2T = PB1  + (size_t)B_*W_;
static const size_t PB2  = PW2T + (size_t)B_*D_*W_;
static const size_t MOM  = PB2  + (size_t)B_*D_;
static const size_t MW1  = MOM;
static const size_t MB1  = MW1  + (size_t)B_*D_*W_;
static const size_t MW2T = MB1  + (size_t)B_*W_;
static const size_t MB2  = MW2T + (size_t)B_*D_*W_;
static const size_t MOMSZ = (size_t)B_*(D_*W_ + W_ + D_*W_ + D_);
static const size_t Q1   = MOM  + MOMSZ;
static const size_t AH   = Q1   + (size_t)B_*SEG_*D_;
static const size_t HBUF = AH   + (size_t)B_*SEG_*W_;
static const size_t COMB = HBUF + (size_t)B_*SEG_*D_;
static const size_t QKV  = COMB + (size_t)B_*T_*D_;
static const size_t ATTN = QKV  + (size_t)B_*T_*3*D_;
static const size_t SEGO = ATTN + (size_t)B_*SEG_*D_;
static const size_t KM   = SEGO + (size_t)B_*SEG_*D_;
static const size_t VM   = KM   + (size_t)B_*SEG_*D_;
static const size_t MEMO = VM   + (size_t)B_*SEG_*D_;
static const size_t WSEND = MEMO + (size_t)B_*SEG_*D_;

// scan-phase buffers ALIAS the QKV region
static const size_t AQ1K  = QKV;
static const size_t AQ1KM = AQ1K  + 32768;
static const size_t AGRAM = AQ1KM + 32768;
static const size_t ADZ1  = AGRAM + 32768;
static const size_t AA1H  = ADZ1  + 32768;
static const size_t AEH   = AA1H  + 32768;
static const size_t AEXR  = AEH + (size_t)B_*SEG_*D_;
static const size_t AEXEE = AEXR + 16384;
// persistent tail
static const size_t COEF  = WSEND;
static const size_t ZEROB = COEF + 512;
static const size_t CBAR  = ZEROB + 128;

__device__ __forceinline__ float sigf(float x) { return 1.f/(1.f+expf(-x)); }

__device__ __forceinline__ void gstore(float* p, float v) {
  __hip_atomic_store(p, v, __ATOMIC_RELAXED, __HIP_MEMORY_SCOPE_AGENT);
}
__device__ __forceinline__ float gload(const float* p) {
  return __hip_atomic_load(p, __ATOMIC_RELAXED, __HIP_MEMORY_SCOPE_AGENT);
}

// RNE bf16 split: a ≈ float(h) + float(l)
__device__ __forceinline__ void bsplit(float a, short& h, short& l) {
  unsigned u = __builtin_bit_cast(unsigned, a);
  unsigned hb = (u + 0x7fffu + ((u >> 16) & 1u)) >> 16;
  h = (short)hb;
  float hf = __builtin_bit_cast(float, hb << 16);
  float r = a - hf;
  unsigned ur = __builtin_bit_cast(unsigned, r);
  unsigned lb = (ur + 0x7fffu + ((ur >> 16) & 1u)) >> 16;
  l = (short)lb;
}

// ------- universal bf16-split MFMA GEMM -------
// C = A@B + bias; BT: B stored [N,K]; SILU epilogue; MUL: C = (A@B+bias)*aux.
// 128x128 tiles; M mult of 128 per batch (guarded anyway); K mult of 32.
template<int BT, int SILU, int MUL>
__global__ __launch_bounds__(256) void k_mf(
    const float* __restrict__ A, const float* __restrict__ Bm,
    const float* __restrict__ bias, float* __restrict__ C,
    const float* __restrict__ aux,
    int M, int N, int K, long sA, long sB, long sC, long sBias, long sAux)
{
  __shared__ short Ah[128][48];
  __shared__ short Al[128][48];
  __shared__ short Bh[32][132];
  __shared__ short Bl[32][132];
  int bz = blockIdx.z;
  A += bz*sA; Bm += bz*sB; C += bz*sC; bias += bz*sBias;
  if (MUL) aux += bz*sAux;
  int n0 = blockIdx.x*128, m0 = blockIdx.y*128;
  int tid = threadIdx.x;
  int wave = tid >> 6, lane = tid & 63;
  int wm = (wave >> 1) * 64, wn = (wave & 1) * 64;
  int lrow = lane & 15, lk = (lane >> 4) * 8;
  int arow0 = min(m0 + (tid >> 1), M-1);
  f32x4 acc[4][4] = {};
  for (int k0 = 0; k0 < K; k0 += 32) {
    __syncthreads();
    { // stage A
      int r = tid >> 1, kq = (tid & 1) * 16;
      const float* ap = A + (long)arow0*K + k0 + kq;
      #pragma unroll
      for (int q = 0; q < 16; q += 4) {
        float4 v = *(const float4*)(ap + q);
        short h0,l0,h1,l1,h2,l2,h3,l3;
        bsplit(v.x,h0,l0); bsplit(v.y,h1,l1); bsplit(v.z,h2,l2); bsplit(v.w,h3,l3);
        *(short4*)&Ah[r][kq+q] = make_short4(h0,h1,h2,h3);
        *(short4*)&Al[r][kq+q] = make_short4(l0,l1,l2,l3);
      }
    }
    if (BT) { // B stored [N,K]: thread reads row n, 16 consecutive k
      int nn = tid >> 1, kq2 = (tid & 1) * 16;
      const float* bp = Bm + (long)(n0+nn)*K + k0 + kq2;
      #pragma unroll
      for (int q = 0; q < 16; q += 4) {
        float4 v = *(const float4*)(bp + q);
        short h0,l0,h1,l1,h2,l2,h3,l3;
        bsplit(v.x,h0,l0); bsplit(v.y,h1,l1); bsplit(v.z,h2,l2); bsplit(v.w,h3,l3);
        Bh[kq2+q+0][nn]=h0; Bh[kq2+q+1][nn]=h1; Bh[kq2+q+2][nn]=h2; Bh[kq2+q+3][nn]=h3;
        Bl[kq2+q+0][nn]=l0; Bl[kq2+q+1][nn]=l1; Bl[kq2+q+2][nn]=l2; Bl[kq2+q+3][nn]=l3;
      }
    } else {
      int kr = tid >> 3, nq = (tid & 7) * 16;
      const float* bp = Bm + (long)(k0 + kr)*N + n0 + nq;
      #pragma unroll
      for (int q = 0; q < 16; q += 4) {
        float4 v = *(const float4*)(bp + q);
        short h0,l0,h1,l1,h2,l2,h3,l3;
        bsplit(v.x,h0,l0); bsplit(v.y,h1,l1); bsplit(v.z,h2,l2); bsplit(v.w,h3,l3);
        *(short4*)&Bh[kr][nq+q] = make_short4(h0,h1,h2,h3);
        *(short4*)&Bl[kr][nq+q] = make_short4(l0,l1,l2,l3);
      }
    }
    __syncthreads();
    bf16x8 bh[4], bl[4];
    #pragma unroll
    for (int nf = 0; nf < 4; nf++) {
      int col = wn + nf*16 + lrow;
      #pragma unroll
      for (int j = 0; j < 8; j++) {
        bh[nf][j] = __builtin_bit_cast(__bf16, Bh[lk+j][col]);
        bl[nf][j] = __builtin_bit_cast(__bf16, Bl[lk+j][col]);
      }
    }
    #pragma unroll
    for (int mf = 0; mf < 4; mf++) {
      int ar2 = wm + mf*16 + lrow;
      bf16x8 ah = *(const bf16x8*)&Ah[ar2][lk];
      bf16x8 al = *(const bf16x8*)&Al[ar2][lk];
      #pragma unroll
      for (int nf = 0; nf < 4; nf++) {
        acc[mf][nf] = __builtin_amdgcn_mfma_f32_16x16x32_bf16(ah, bh[nf], acc[mf][nf], 0, 0, 0);
        acc[mf][nf] = __builtin_amdgcn_mfma_f32_16x16x32_bf16(ah, bl[nf], acc[mf][nf], 0, 0, 0);
        acc[mf][nf] = __builtin_amdgcn_mfma_f32_16x16x32_bf16(al, bh[nf], acc[mf][nf], 0, 0, 0);
      }
    }
  }
  #pragma unroll
  for (int mf = 0; mf < 4; mf++) {
    #pragma unroll
    for (int nf = 0; nf < 4; nf++) {
      int col = n0 + wn + nf*16 + lrow;
      float bv = bias[col];
      #pragma unroll
      for (int j = 0; j < 4; j++) {
        int row = m0 + wm + mf*16 + (lane >> 4)*4 + j;
        if (row < M) {
          float v = acc[mf][nf][j] + bv;
          if (SILU) v = v * sigf(v);
          if (MUL)  v *= aux[(long)row*N + col];
          C[(long)row*N + col] = v;
        }
      }
    }
  }
}

// ------- dual-output 64x64 fp32 GEMM: C1=A@B1, C2=A@B2 (no bias) ----
__global__ __launch_bounds__(256) void k_gemm2(
    const float* __restrict__ A, const float* __restrict__ B1,
    const float* __restrict__ B2, float* __restrict__ C1, float* __restrict__ C2,
    int K, long sA, long sB, long sC)
{
  __shared__ float As[16][68];
  __shared__ float B1s[16][68];
  __shared__ float B2s[16][68];
  int bz = blockIdx.z;
  A += bz*sA; B1 += bz*sB; B2 += bz*sB; C1 += bz*sC; C2 += bz*sC;
  int n0 = blockIdx.x*64, m0 = blockIdx.y*64;
  int tid = threadIdx.x;
  int tx = tid & 15, ty = tid >> 4;
  int r  = tid >> 2;
  int kq = (tid & 3) * 4;
  float acc1[4][4] = {}, acc2[4][4] = {};
  for (int k0 = 0; k0 < K; k0 += 16) {
    {
      float4 v = *(const float4*)(A + (long)(m0+r)*K + k0 + kq);
      As[kq+0][r]=v.x; As[kq+1][r]=v.y; As[kq+2][r]=v.z; As[kq+3][r]=v.w;
    }
    {
      int c = tid & 63, r4 = tid >> 6;
      #pragma unroll
      for (int p = 0; p < 4; p++) {
        int kk = r4 + p*4;
        B1s[kk][c] = B1[(long)(k0+kk)*W_ + n0 + c];
        B2s[kk][c] = B2[(long)(k0+kk)*W_ + n0 + c];
      }
    }
    __syncthreads();
    #pragma unroll
    for (int kk = 0; kk < 16; kk++) {
      float av[4], b1v[4], b2v[4];
      #pragma unroll
      for (int i=0;i<4;i++) av[i] = As[kk][ty*4+i];
      #pragma unroll
      for (int j=0;j<4;j++) { b1v[j] = B1s[kk][tx*4+j]; b2v[j] = B2s[kk][tx*4+j]; }
      #pragma unroll
      for (int i=0;i<4;i++)
        #pragma unroll
        for (int j=0;j<4;j++) {
          acc1[i][j] = fmaf(av[i], b1v[j], acc1[i][j]);
          acc2[i][j] = fmaf(av[i], b2v[j], acc2[i][j]);
        }
    }
    __syncthreads();
  }
  #pragma unroll
  for (int i=0;i<4;i++) {
    int row = m0 + ty*4 + i;
    #pragma unroll
    for (int j=0;j<4;j++) {
      int col = n0 + tx*4 + j;
      C1[(long)row*W_ + col] = acc1[i][j];
      C2[(long)row*W_ + col] = acc2[i][j];
    }
  }
}

// ------- QKV MFMA GEMM with fused concat -------
__global__ __launch_bounds__(256) void k_qkv_mfma(
    const float* __restrict__ pers, const float* __restrict__ hbuf,
    const float* __restrict__ xemb, int s,
    const float* __restrict__ Bm, const float* __restrict__ bias,
    float* __restrict__ C)
{
  __shared__ short Ah[128][48];
  __shared__ short Al[128][48];
  __shared__ short Bh[32][132];
  __shared__ short Bl[32][132];
  const int M = B_*T_, N = 3*D_, K = D_;
  int n0 = blockIdx.x*128, m0 = blockIdx.y*128;
  int tid = threadIdx.x;
  int wave = tid >> 6, lane = tid & 63;
  int wm = (wave >> 1) * 64, wn = (wave & 1) * 64;
  int lrow = lane & 15, lk = (lane >> 4) * 8;
  int grow = min(m0 + (tid >> 1), M-1);
  int b = grow >= T_ ? 1 : 0;
  int rt = grow - b*T_;
  const float* asrc;
  if (rt < NPT_)            asrc = pers + (long)rt*D_;
  else if (rt < NPT_+SEG_)  asrc = hbuf + ((long)b*SEG_ + (rt-NPT_))*D_;
  else                      asrc = xemb + ((long)b*N_ + s*SEG_ + (rt-NPT_-SEG_))*D_;
  f32x4 acc[4][4] = {};
  for (int k0 = 0; k0 < K; k0 += 32) {
    __syncthreads();
    {
      int r = tid >> 1, kq = (tid & 1) * 16;
      const float* ap = asrc + k0 + kq;
      #pragma unroll
      for (int q = 0; q < 16; q += 4) {
        float4 v = *(const float4*)(ap + q);
        short h0,l0,h1,l1,h2,l2,h3,l3;
        bsplit(v.x,h0,l0); bsplit(v.y,h1,l1); bsplit(v.z,h2,l2); bsplit(v.w,h3,l3);
        *(short4*)&Ah[r][kq+q] = make_short4(h0,h1,h2,h3);
        *(short4*)&Al[r][kq+q] = make_short4(l0,l1,l2,l3);
      }
    }
    {
      int kr = tid >> 3, nq = (tid & 7) * 16;
      const float* bp = Bm + (long)(k0 + kr)*N + n0 + nq;
      #pragma unroll
      for (int q = 0; q < 16; q += 4) {
        float4 v = *(const float4*)(bp + q);
        short h0,l0,h1,l1,h2,l2,h3,l3;
        bsplit(v.x,h0,l0); bsplit(v.y,h1,l1); bsplit(v.z,h2,l2); bsplit(v.w,h3,l3);
        *(short4*)&Bh[kr][nq+q] = make_short4(h0,h1,h2,h3);
        *(short4*)&Bl[kr][nq+q] = make_short4(l0,l1,l2,l3);
      }
    }
    __syncthreads();
    bf16x8 bh[4], bl[4];
    #pragma unroll
    for (int nf = 0; nf < 4; nf++) {
      int col = wn + nf*16 + lrow;
      #pragma unroll
      for (int j = 0; j < 8; j++) {
        bh[nf][j] = __builtin_bit_cast(__bf16, Bh[lk+j][col]);
        bl[nf][j] = __builtin_bit_cast(__bf16, Bl[lk+j][col]);
      }
    }
    #pragma unroll
    for (int mf = 0; mf < 4; mf++) {
      int ar2 = wm + mf*16 + lrow;
      bf16x8 ah = *(const bf16x8*)&Ah[ar2][lk];
      bf16x8 al = *(const bf16x8*)&Al[ar2][lk];
      #pragma unroll
      for (int nf = 0; nf < 4; nf++) {
        acc[mf][nf] = __builtin_amdgcn_mfma_f32_16x16x32_bf16(ah, bh[nf], acc[mf][nf], 0, 0, 0);
        acc[mf][nf] = __builtin_amdgcn_mfma_f32_16x16x32_bf16(ah, bl[nf], acc[mf][nf], 0, 0, 0);
        acc[mf][nf] = __builtin_amdgcn_mfma_f32_16x16x32_bf16(al, bh[nf], acc[mf][nf], 0, 0, 0);
      }
    }
  }
  #pragma unroll
  for (int mf = 0; mf < 4; mf++) {
    #pragma unroll
    for (int nf = 0; nf < 4; nf++) {
      int col = n0 + wn + nf*16 + lrow;
      float bv = bias[col];
      #pragma unroll
      for (int j = 0; j < 4; j++) {
        int row = m0 + wm + mf*16 + (lane >> 4)*4 + j;
        if (row < M) C[(long)row*N + col] = acc[mf][nf][j] + bv;
      }
    }
  }
}

// ------- fused K/V/Q projection via bf16-split MFMA ----
__global__ __launch_bounds__(256) void k_gemmkvq_m(
    const float* __restrict__ A,
    const float* __restrict__ Wk, const float* __restrict__ bk,
    const float* __restrict__ Wv, const float* __restrict__ bv,
    const float* __restrict__ Wq, const float* __restrict__ bq,
    float* __restrict__ KMo, float* __restrict__ VMo, float* __restrict__ Q1o)
{
  __shared__ short Ah[128][48];
  __shared__ short Al[128][48];
  __shared__ short Bh[32][132];
  __shared__ short Bl[32][132];
  int bx = blockIdx.x;
  int sel = bx >> 3;
  int n0 = (bx & 7) * 128;
  int m0 = blockIdx.y * 128;
  const float* Bm   = sel == 0 ? Wk : sel == 1 ? Wv : Wq;
  const float* bias = sel == 0 ? bk : sel == 1 ? bv : bq;
  float* C          = sel == 0 ? KMo : sel == 1 ? VMo : Q1o;
  int tid = threadIdx.x;
  int wave = tid >> 6, lane = tid & 63;
  int wm = (wave >> 1) * 64, wn = (wave & 1) * 64;
  int lrow = lane & 15, lk = (lane >> 4) * 8;
  f32x4 acc[4][4] = {};
  for (int k0 = 0; k0 < D_; k0 += 32) {
    __syncthreads();
    {
      int r = tid >> 1, kq = (tid & 1) * 16;
      const float* ap = A + (long)(m0 + r)*D_ + k0 + kq;
      #pragma unroll
      for (int q = 0; q < 16; q += 4) {
        float4 v = *(const float4*)(ap + q);
        short h0,l0,h1,l1,h2,l2,h3,l3;
        bsplit(v.x,h0,l0); bsplit(v.y,h1,l1); bsplit(v.z,h2,l2); bsplit(v.w,h3,l3);
        *(short4*)&Ah[r][kq+q] = make_short4(h0,h1,h2,h3);
        *(short4*)&Al[r][kq+q] = make_short4(l0,l1,l2,l3);
      }
    }
    {
      int kr = tid >> 3, nq = (tid & 7) * 16;
      const float* bp = Bm + (long)(k0 + kr)*D_ + n0 + nq;
      #pragma unroll
      for (int q = 0; q < 16; q += 4) {
        float4 v = *(const float4*)(bp + q);
        short h0,l0,h1,l1,h2,l2,h3,l3;
        bsplit(v.x,h0,l0); bsplit(v.y,h1,l1); bsplit(v.z,h2,l2); bsplit(v.w,h3,l3);
        *(short4*)&Bh[kr][nq+q] = make_short4(h0,h1,h2,h3);
        *(short4*)&Bl[kr][nq+q] = make_short4(l0,l1,l2,l3);
      }
    }
    __syncthreads();
    bf16x8 bh[4], bl[4];
    #pragma unroll
    for (int nf = 0; nf < 4; nf++) {
      int col = wn + nf*16 + lrow;
      #pragma unroll
      for (int j = 0; j < 8; j++) {
        bh[nf][j] = __builtin_bit_cast(__bf16, Bh[lk+j][col]);
        bl[nf][j] = __builtin_bit_cast(__bf16, Bl[lk+j][col]);
      }
    }
    #pragma unroll
    for (int mf = 0; mf < 4; mf++) {
      int ar2 = wm + mf*16 + lrow;
      bf16x8 ah = *(const bf16x8*)&Ah[ar2][lk];
      bf16x8 al = *(const bf16x8*)&Al[ar2][lk];
      #pragma unroll
      for (int nf = 0; nf < 4; nf++) {
        acc[mf][nf] = __builtin_amdgcn_mfma_f32_16x16x32_bf16(ah, bh[nf], acc[mf][nf], 0, 0, 0);
        acc[mf][nf] = __builtin_amdgcn_mfma_f32_16x16x32_bf16(ah, bl[nf], acc[mf][nf], 0, 0, 0);
        acc[mf][nf] = __builtin_amdgcn_mfma_f32_16x16x32_bf16(al, bh[nf], acc[mf][nf], 0, 0, 0);
      }
    }
  }
  #pragma unroll
  for (int mf = 0; mf < 4; mf++) {
    #pragma unroll
    for (int nf = 0; nf < 4; nf++) {
      int col = n0 + wn + nf*16 + lrow;
      float bvx = bias[col];
      #pragma unroll
      for (int j = 0; j < 4; j++) {
        int row = m0 + wm + mf*16 + (lane >> 4)*4 + j;
        C[(long)row*D_ + col] = acc[mf][nf][j] + bvx;
      }
    }
  }
}

// ------- head GEMM via bf16-split MFMA -------
__global__ __launch_bounds__(256) void k_head_mfma(
    const float* __restrict__ A, const float* __restrict__ Bm,
    const float* __restrict__ bias, float* __restrict__ C,
    int M, int N, int K)
{
  __shared__ short Ah[128][48];
  __shared__ short Al[128][48];
  __shared__ short Bh[32][132];
  __shared__ short Bl[32][132];
  int n0 = blockIdx.x*128, m0 = blockIdx.y*128;
  int tid = threadIdx.x;
  int wave = tid >> 6, lane = tid & 63;
  int wm = (wave >> 1) * 64, wn = (wave & 1) * 64;
  int lrow = lane & 15, lk = (lane >> 4) * 8;
  f32x4 acc[4][4] = {};
  for (int k0 = 0; k0 < K; k0 += 32) {
    __syncthreads();
    {
      int r = tid >> 1, kq = (tid & 1) * 16;
      const float* ap = A + (long)(m0 + r)*K + k0 + kq;
      #pragma unroll
      for (int q = 0; q < 16; q += 4) {
        float4 v = *(const float4*)(ap + q);
        short h0,l0,h1,l1,h2,l2,h3,l3;
        bsplit(v.x,h0,l0); bsplit(v.y,h1,l1); bsplit(v.z,h2,l2); bsplit(v.w,h3,l3);
        *(short4*)&Ah[r][kq+q] = make_short4(h0,h1,h2,h3);
        *(short4*)&Al[r][kq+q] = make_short4(l0,l1,l2,l3);
      }
    }
    {
      int kr = tid >> 3, nq = (tid & 7) * 16;
      const float* bp = Bm + (long)(k0 + kr)*N + n0 + nq;
      #pragma unroll
      for (int q = 0; q < 16; q += 4) {
        float4 v = *(const float4*)(bp + q);
        short h0,l0,h1,l1,h2,l2,h3,l3;
        bsplit(v.x,h0,l0); bsplit(v.y,h1,l1); bsplit(v.z,h2,l2); bsplit(v.w,h3,l3);
        *(short4*)&Bh[kr][nq+q] = make_short4(h0,h1,h2,h3);
        *(short4*)&Bl[kr][nq+q] = make_short4(l0,l1,l2,l3);
      }
    }
    __syncthreads();
    bf16x8 bh[4], bl[4];
    #pragma unroll
    for (int nf = 0; nf < 4; nf++) {
      int col = wn + nf*16 + lrow;
      #pragma unroll
      for (int j = 0; j < 8; j++) {
        bh[nf][j] = __builtin_bit_cast(__bf16, Bh[lk+j][col]);
        bl[nf][j] = __builtin_bit_cast(__bf16, Bl[lk+j][col]);
      }
    }
    #pragma unroll
    for (int mf = 0; mf < 4; mf++) {
      int arow2 = wm + mf*16 + lrow;
      bf16x8 ah = *(const bf16x8*)&Ah[arow2][lk];
      bf16x8 al = *(const bf16x8*)&Al[arow2][lk];
      #pragma unroll
      for (int nf = 0; nf < 4; nf++) {
        acc[mf][nf] = __builtin_amdgcn_mfma_f32_16x16x32_bf16(ah, bh[nf], acc[mf][nf], 0, 0, 0);
        acc[mf][nf] = __builtin_amdgcn_mfma_f32_16x16x32_bf16(ah, bl[nf], acc[mf][nf], 0, 0, 0);
        acc[mf][nf] = __builtin_amdgcn_mfma_f32_16x16x32_bf16(al, bh[nf], acc[mf][nf], 0, 0, 0);
      }
    }
  }
  #pragma unroll
  for (int mf = 0; mf < 4; mf++) {
    #pragma unroll
    for (int nf = 0; nf < 4; nf++) {
      int col = n0 + wn + nf*16 + lrow;
      float bv = bias[col];
      #pragma unroll
      for (int j = 0; j < 4; j++) {
        int row = m0 + wm + mf*16 + (lane >> 4)*4 + j;
        C[(long)row*N + col] = acc[mf][nf][j] + bv;
      }
    }
  }
}

// ---------------- small kernels ----------------
__global__ void k_embed(const int* __restrict__ x, const float* __restrict__ emb,
                        float* __restrict__ xe)
{
  int row = blockIdx.x, tid = threadIdx.x;
  int idx = x[row];
  float4 v = *(const float4*)(emb + (long)idx*D_ + tid*4);
  *(float4*)(xe + (long)row*D_ + tid*4) = v;
}

#define PER_ 263296L
__global__ void k_init(const float* __restrict__ mW1in, const float* __restrict__ mb1in,
                       const float* __restrict__ mW2in, const float* __restrict__ mb2in,
                       float* __restrict__ pW1, float* __restrict__ pb1,
                       float* __restrict__ pW2T, float* __restrict__ pb2)
{
  long g = (long)blockIdx.x*256 + threadIdx.x;
  if (g >= 2*PER_) return;
  int b = (int)(g / PER_);
  long rr = g % PER_;
  if (rr < 131072)       pW1[(long)b*131072 + rr] = mW1in[rr];
  else if (rr < 131200)  pb1[b*W_ + (rr-131072)] = mb1in[rr-131072];
  else if (rr < 262272) { long l = rr-131200; int j=(int)(l>>7), h=(int)(l&127);
                          pW2T[(long)b*131072 + l] = mW2in[(long)h*D_ + j]; }
  else                   pb2[b*D_ + (rr-262272)] = mb2in[rr-262272];
}

__global__ void k_coef(float* __restrict__ c)
{
  if (blockIdx.x == 0 && threadIdx.x == 0) {
    c[0] = 1.f; c[128] = 1.f;
    float A = 1.f, eta_d = 1.f;
    for (int d = 1; d < 128; d++) {
      eta_d *= ETA_;
      A = PDEC_*A + eta_d;
      c[d] = A;
      c[128 + d] = eta_d;
    }
    c[256] = 1.f;
    float bp = 1.f;
    for (int t = 1; t <= 128; t++) { bp *= PDEC_; c[256 + t] = bp; }
  }
}

__global__ __launch_bounds__(256) void k_l2n(float* __restrict__ X)
{
  long row = blockIdx.x;
  float* p = X + row*D_;
  int tid = threadIdx.x;
  float4 v = *(float4*)(p + tid*4);
  float ss = v.x*v.x + v.y*v.y + v.z*v.z + v.w*v.w;
  for (int o=32;o;o>>=1) ss += __shfl_xor(ss,o);
  __shared__ float wsum[4];
  if ((tid&63)==0) wsum[tid>>6] = ss;
  __syncthreads();
  float tot = wsum[0]+wsum[1]+wsum[2]+wsum[3];
  float sc = 1.f/(sqrtf(tot)+EPSN_);
  v.x*=sc; v.y*=sc; v.z*=sc; v.w*=sc;
  *(float4*)(p + tid*4) = v;
}

// dual-array l2n: rows [0,R) from X1, rows [R,2R) from X2
__global__ __launch_bounds__(256) void k_l2n2(float* __restrict__ X1, float* __restrict__ X2, int R)
{
  int row = blockIdx.x;
  float* p = (row < R ? X1 + (long)row*D_ : X2 + (long)(row-R)*D_);
  int tid = threadIdx.x;
  float4 v = *(float4*)(p + tid*4);
  float ss = v.x*v.x + v.y*v.y + v.z*v.z + v.w*v.w;
  for (int o=32;o;o>>=1) ss += __shfl_xor(ss,o);
  __shared__ float wsum[4];
  if ((tid&63)==0) wsum[tid>>6] = ss;
  __syncthreads();
  float tot = wsum[0]+wsum[1]+wsum[2]+wsum[3];
  float sc = 1.f/(sqrtf(tot)+EPSN_);
  v.x*=sc; v.y*=sc; v.z*=sc; v.w*=sc;
  *(float4*)(p + tid*4) = v;
}

__global__ __launch_bounds__(256) void k_attn(const float* __restrict__ qkv,
                                              float* __restrict__ outp)
{
  __shared__ float sQ[16][68];
  __shared__ float sKV[64][68];
  __shared__ float sS[16][273];
  int qt = blockIdx.x, head = blockIdx.y, b = blockIdx.z;
  int tid = threadIdx.x;
  const float* base = qkv + (long)b*T_*3*D_;
  int qoff = head*HD_, koff = D_ + head*HD_, voff = 2*D_ + head*HD_;
  int qrow0 = NPT_ + SEG_ + qt*16;
  {
    int rr = tid>>4, c4 = (tid&15)*4;
    float4 v = *(const float4*)(base + (long)(qrow0+rr)*3*D_ + qoff + c4);
    sQ[rr][c4]=v.x; sQ[rr][c4+1]=v.y; sQ[rr][c4+2]=v.z; sQ[rr][c4+3]=v.w;
  }
  __syncthreads();
  for (int j0 = 0; j0 < T_; j0 += 64) {
    int chunk = min(64, T_ - j0);
    {
      int jj = tid>>2, cq = (tid&3)*16;
      if (jj < chunk) {
        #pragma unroll
        for (int q4=0;q4<4;q4++) {
          float4 v = *(const float4*)(base + (long)(j0+jj)*3*D_ + koff + cq + q4*4);
          sKV[jj][cq+q4*4]=v.x; sKV[jj][cq+q4*4+1]=v.y; sKV[jj][cq+q4*4+2]=v.z; sKV[jj][cq+q4*4+3]=v.w;
        }
      }
    }
    __syncthreads();
    int rr = tid>>4, jj0 = tid&15;
    #pragma unroll
    for (int p=0;p<4;p++) {
      int jj = jj0 + p*16;
      if (jj < chunk) {
        float s = 0.f;
        #pragma unroll 8
        for (int c=0;c<HD_;c++) s = fmaf(sQ[rr][c], sKV[jj][c], s);
        s *= 0.125f;
        int jg = j0 + jj, qg = qrow0 + rr;
        if (jg > qg) s = -3.0e38f;
        sS[rr][jg] = s;
      }
    }
    __syncthreads();
  }
  {
    int rr = tid>>4, l16 = tid&15;
    float m = -3.4e38f;
    for (int j=l16; j<T_; j+=16) m = fmaxf(m, sS[rr][j]);
    for (int o=8;o;o>>=1) m = fmaxf(m, __shfl_xor(m,o));
    float sum = 0.f;
    for (int j=l16; j<T_; j+=16) { float e = expf(sS[rr][j]-m); sS[rr][j] = e; sum += e; }
    for (int o=8;o;o>>=1) sum += __shfl_xor(sum,o);
    float inv = 1.f/sum;
    for (int j=l16; j<T_; j+=16) sS[rr][j] *= inv;
  }
  __syncthreads();
  float acc[4] = {0.f,0.f,0.f,0.f};
  int rr = tid>>4, c4 = (tid&15)*4;
  for (int j0 = 0; j0 < T_; j0 += 64) {
    int chunk = min(64, T_ - j0);
    {
      int jj = tid>>2, cq = (tid&3)*16;
      if (jj < chunk) {
        #pragma unroll
        for (int q4=0;q4<4;q4++) {
          float4 v = *(const float4*)(base + (long)(j0+jj)*3*D_ + voff + cq + q4*4);
          sKV[jj][cq+q4*4]=v.x; sKV[jj][cq+q4*4+1]=v.y; sKV[jj][cq+q4*4+2]=v.z; sKV[jj][cq+q4*4+3]=v.w;
        }
      }
    }
    __syncthreads();
    for (int jj=0; jj<chunk; jj++) {
      float p = sS[rr][j0+jj];
      #pragma unroll
      for (int i=0;i<4;i++) acc[i] = fmaf(p, sKV[jj][c4+i], acc[i]);
    }
    __syncthreads();
  }
  float4 o4 = make_float4(acc[0],acc[1],acc[2],acc[3]);
  *(float4*)(outp + ((long)(b*SEG_) + qt*16 + rr)*D_ + head*HD_ + c4) = o4;
}

// ------- fence-free flag barrier ---------
__device__ __forceinline__ void gbar(int* flags, int blk, int gen)
{
  asm volatile("s_waitcnt vmcnt(0) lgkmcnt(0)" ::: "memory");
  __syncthreads();
  if (threadIdx.x == 0)
    __hip_atomic_store(flags + blk*FSTR_, gen, __ATOMIC_RELAXED, __HIP_MEMORY_SCOPE_AGENT);
  if (threadIdx.x < NB2_) {
    while (__hip_atomic_load(flags + threadIdx.x*FSTR_, __ATOMIC_RELAXED,
                             __HIP_MEMORY_SCOPE_AGENT) < gen)
      __builtin_amdgcn_s_sleep(1);
  }
  __syncthreads();
}

// ---- persistent token-space scan (round-10 version: reg-W, 1 barrier) ----
__global__ __launch_bounds__(256) void k_scan(
  const float* __restrict__ pW2T, const float* __restrict__ mW2T,
  float* __restrict__ pb1, float* __restrict__ mb1,
  float* __restrict__ pb2, float* __restrict__ mb2,
  const float* __restrict__ Vm,
  const float* __restrict__ q1k, const float* __restrict__ q1km,
  const float* __restrict__ G,
  float* __restrict__ dz1o, float* __restrict__ a1o, float* __restrict__ eo,
  float* __restrict__ exR, float* __restrict__ exEE,
  const float* __restrict__ coef, int* __restrict__ barbase, int seg)
{
  __shared__ float sDZ[128][129];
  __shared__ float sA1[128][129];
  __shared__ float sEh[128][33];
  __shared__ float sB1[128], sMB1[128], sZ1[128], sR[128];
  __shared__ float sB2[32], sMB2[32];
  __shared__ float sAt[128];
  __shared__ float sBp[129];
  __shared__ float sGc[128];
  __shared__ float sS[128];
  __shared__ float sEEc[128];

  int b = blockIdx.y, blk = blockIdx.x, tid = threadIdx.x;
  int j0 = blk*32;
  int* flags = barbase + b*(NB2_*FSTR_);
  int gbase = seg*200;
  const float* W0 = pW2T + (long)b*131072;
  const float* Wm = mW2T + (long)b*131072;

  int jD = tid >> 3, lD = tid & 7;
  float rD0[16], rDm[16];
  #pragma unroll
  for (int k = 0; k < 16; k++) {
    rD0[k] = W0[(long)(j0+jD)*128 + lD + 8*k];
    rDm[k] = Wm[(long)(j0+jD)*128 + lD + 8*k];
  }
  int hE = tid >> 1, halfE = tid & 1;
  float rE0[16], rEm[16];
  #pragma unroll
  for (int q = 0; q < 16; q++) {
    rE0[q] = W0[(long)(j0 + halfE*16 + q)*128 + hE];
    rEm[q] = Wm[(long)(j0 + halfE*16 + q)*128 + hE];
  }

  if (tid < 128) { sAt[tid] = coef[tid]; sB1[tid] = pb1[b*W_+tid]; sMB1[tid] = mb1[b*W_+tid]; }
  else if (tid < 160) { int j = tid-128; sB2[j] = pb2[b*D_+j0+j]; sMB2[j] = mb2[b*D_+j0+j]; }
  for (int i = tid; i < 129; i += 256) sBp[i] = coef[256+i];
  __syncthreads();

  for (int t = 0; t < SEG_; ++t) {
    int par = t & 1;
    float bp = sBp[t];
    float ca = (t>0) ? ETA_*sAt[t-1] : 0.f;

    // ---- A: bias recurrences, G-row prescale, q1k loads ----
    float rq1k = 0.f, rq1km = 0.f;
    if (tid < 128) {
      rq1k  = q1k [((long)b*SEG_+t)*W_ + tid];
      rq1km = q1km[((long)b*SEG_+t)*W_ + tid];
      if (t > 0) {
        float mm = ETA_*sMB1[tid] - THETA_*sDZ[t-1][tid];
        sMB1[tid] = mm; sB1[tid] = PDEC_*sB1[tid] + mm;
      }
      if (tid < t) sGc[tid] = sAt[t-1-tid]*G[((long)b*SEG_+t)*SEG_ + tid];
    } else if (tid < 160) {
      int j = tid-128;
      if (t > 0) {
        float mm = ETA_*sMB2[j] - 2.f*THETA_*sEh[t-1][j];
        sMB2[j] = mm; sB2[j] = PDEC_*sB2[j] + mm;
      }
    }
    __syncthreads();

    // ---- B: z1/a1 for ALL h ----
    if (tid < 128) {
      float acc = 0.f;
      for (int u = 0; u < t; ++u) acc = fmaf(sGc[u], sDZ[u][tid], acc);
      float z1 = bp*rq1k + ca*rq1km + sB1[tid] - THETA_*acc;
      sZ1[tid] = z1;
      sA1[t][tid] = z1 * sigf(z1);
    }
    __syncthreads();

    // ---- C: sS scalars from in-block a1 Gram ----
    if (tid < t) {
      float acc = 0.f;
      #pragma unroll 8
      for (int h = 0; h < 128; ++h) acc = fmaf(sA1[tid][h], sA1[t][h], acc);
      sS[tid] = -2.f*THETA_*sAt[t-1-tid]*acc;
    }
    __syncthreads();

    // ---- D: e slice (W in registers) ----
    {
      float g = 0.f, gm = 0.f;
      #pragma unroll
      for (int k = 0; k < 16; k++) {
        float a = sA1[t][lD + 8*k];
        g  = fmaf(rD0[k], a, g);
        gm = fmaf(rDm[k], a, gm);
      }
      float corr = 0.f;
      for (int u = lD; u < t; u += 8) corr = fmaf(sS[u], sEh[u][jD], corr);
      float tot = bp*g + ca*gm + corr;
      tot += __shfl_xor(tot,4); tot += __shfl_xor(tot,2); tot += __shfl_xor(tot,1);
      if (lD == 0) sEh[t][jD] = tot + sB2[jD] - Vm[((long)b*SEG_+t)*D_ + j0+jD];
    }
    __syncthreads();

    // ---- E: r partials (W in registers) + ee partials ----
    {
      float racc = 0.f;
      #pragma unroll
      for (int q = 0; q < 16; ++q) {
        float w = bp*rE0[q] + ca*rEm[q];
        racc = fmaf(w, sEh[t][halfE*16 + q], racc);
      }
      racc += __shfl_xor(racc,1);
      if (halfE == 0) gstore(&exR[(((long)par*B_ + b)*NB2_ + blk)*W_ + hE], racc);
      if (hE < t) {
        float eacc = 0.f;
        #pragma unroll
        for (int q = 0; q < 16; ++q)
          eacc = fmaf(sEh[hE][halfE*16 + q], sEh[t][halfE*16 + q], eacc);
        eacc += __shfl_xor(eacc,1);
        if (halfE == 0) gstore(&exEE[(((long)par*B_ + b)*NB2_ + blk)*W_ + hE], eacc);
      }
    }
    gbar(flags, blk, gbase + t + 1);

    // ---- F: gather r/ee, dz1 full-h ----
    {
      float racc = 0.f;
      #pragma unroll
      for (int k = 0; k < 16; ++k)
        racc += gload(&exR[(((long)par*B_ + b)*NB2_ + halfE*16 + k)*W_ + hE]);
      racc += __shfl_xor(racc,1);
      if (halfE == 0) sR[hE] = racc;
      if (hE < t) {
        float eacc = 0.f;
        #pragma unroll
        for (int k = 0; k < 16; ++k)
          eacc += gload(&exEE[(((long)par*B_ + b)*NB2_ + halfE*16 + k)*W_ + hE]);
        eacc += __shfl_xor(eacc,1);
        if (halfE == 0) sEEc[hE] = -2.f*THETA_*sAt[t-1-hE]*eacc;
      }
    }
    __syncthreads();
    if (tid < 128) {
      float macc = 0.f;
      for (int u = 0; u < t; ++u) macc = fmaf(sEEc[u], sA1[u][tid], macc);
      float z = sZ1[tid], sg = sigf(z);
      sDZ[t][tid] = 2.f*(sR[tid] + macc)*sg*(1.f + z*(1.f - sg));
    }
    __syncthreads();
  }

  // ---- epilogue ----
  if (tid < 128) {
    if (blk == 0) {
      float mm = ETA_*sMB1[tid] - THETA_*sDZ[127][tid];
      mb1[b*W_ + tid] = mm;
      pb1[b*W_ + tid] = PDEC_*sB1[tid] + mm;
    }
  } else if (tid < 160) {
    int j = tid-128;
    float mm = ETA_*sMB2[j] - 2.f*THETA_*sEh[127][j];
    mb2[b*D_ + j0+j] = mm;
    pb2[b*D_ + j0+j] = PDEC_*sB2[j] + mm;
  }
  for (int i = tid; i < 128*4; i += 256) {
    int t2 = i >> 2, hh = (i & 3) + blk*4;
    dz1o[((long)b*SEG_+t2)*W_ + hh] = sDZ[t2][hh];
    a1o [((long)b*SEG_+t2)*W_ + hh] = sA1[t2][hh];
  }
  for (int i = tid; i < 128*32; i += 256) {
    int t2 = i >> 5, jj = i & 31;
    eo[((long)b*SEG_+t2)*D_ + j0+jj] = sEh[t2][jj];
  }
}

// ---------------- weight/momentum reconstruction --------------------------
__global__ __launch_bounds__(256) void k_recon(
  float* __restrict__ pW1, float* __restrict__ mW1,
  float* __restrict__ pW2T, float* __restrict__ mW2T,
  const float* __restrict__ KMp, const float* __restrict__ Eh,
  const float* __restrict__ DZ1, const float* __restrict__ A1h,
  const float* __restrict__ coef)
{
  __shared__ float s1[16][33];
  __shared__ float s2[16][65];
  __shared__ float sCA[128], sCE[128];
  int dt = blockIdx.x, ht = blockIdx.y, kb = blockIdx.z;
  int kind = kb >> 1, b = kb & 1;
  int tid = threadIdx.x;
  int d0 = dt*32, hb = ht*64;
  const float* in1 = (kind ? Eh : KMp) + (long)b*SEG_*D_;
  const float* in2 = (kind ? A1h : DZ1) + (long)b*SEG_*W_;
  float* Pb = (kind ? pW2T : pW1) + (long)b*131072;
  float* Mb = (kind ? mW2T : mW1) + (long)b*131072;
  float f = kind ? -2.f*THETA_ : -THETA_;
  if (tid < 128) {
    sCA[tid] = f*coef[127 - tid];
    sCE[tid] = f*coef[128 + 127 - tid];
  }
  __syncthreads();
  int dd = tid >> 3, le = tid & 7;
  float accP[8] = {}, accM[8] = {};
  for (int u0 = 0; u0 < 128; u0 += 16) {
    for (int i = tid; i < 16*32; i += 256) {
      int uu = i >> 5, d2 = i & 31;
      s1[uu][d2] = in1[(long)(u0+uu)*D_ + d0 + d2];
    }
    for (int i = tid; i < 16*64; i += 256) {
      int uu = i >> 6, hl = i & 63;
      s2[uu][hl] = in2[(long)(u0+uu)*W_ + hb + hl];
    }
    __syncthreads();
    #pragma unroll
    for (int uu = 0; uu < 16; uu++) {
      float a = s1[uu][dd];
      float cAu = sCA[u0+uu], cEu = sCE[u0+uu];
      #pragma unroll
      for (int k = 0; k < 8; k++) {
        float v = a * s2[uu][k*8 + le];
        accP[k] = fmaf(cAu, v, accP[k]);
        accM[k] = fmaf(cEu, v, accM[k]);
      }
    }
    __syncthreads();
  }
  float b128 = coef[256 + 128];
  float eA   = ETA_*coef[127];
  float e128 = ETA_*coef[128 + 127];
  #pragma unroll
  for (int k = 0; k < 8; k++) {
    long idx = (long)(d0+dd)*W_ + hb + k*8 + le;
    float Po = Pb[idx], Mo = Mb[idx];
    Pb[idx] = b128*Po + eA*Mo + accP[k];
    Mb[idx] = e128*Mo + accM[k];
  }
}

// ---------------- host launcher ----------------
extern "C" void kernel_launch(void* const* d_in, const int* in_sizes, int n_in,
                              void* d_out, int out_size, void* d_ws, size_t ws_size,
                              hipStream_t stream)
{
  (void)in_sizes; (void)n_in; (void)out_size; (void)ws_size;
  const int*   x     = (const int*)  d_in[0];
  const float* emb   = (const float*)d_in[1];
  const float* pers  = (const float*)d_in[2];
  const float* Wq    = (const float*)d_in[3];
  const float* bq    = (const float*)d_in[4];
  const float* Wk    = (const float*)d_in[5];
  const float* bk    = (const float*)d_in[6];
  const float* Wv    = (const float*)d_in[7];
  const float* bv    = (const float*)d_in[8];
  const float* aiw   = (const float*)d_in[9];
  const float* aib   = (const float*)d_in[10];
  const float* aow   = (const float*)d_in[11];
  const float* aob   = (const float*)d_in[12];
  const float* mW1in = (const float*)d_in[13];
  const float* mb1in = (const float*)d_in[14];
  const float* mW2in = (const float*)d_in[15];
  const float* mb2in = (const float*)d_in[16];
  const float* headw = (const float*)d_in[17];
  const float* headb = (const float*)d_in[18];
  float* out = (float*)d_out;
  float* ws  = (float*)d_ws;

  hipMemsetAsync(ws + MOM, 0, MOMSZ*sizeof(float), stream);
  hipMemsetAsync(ws + ZEROB, 0, 128*sizeof(float), stream);
  hipMemsetAsync(ws + CBAR, 0, (size_t)B_*NB2_*FSTR_*sizeof(int), stream);
  k_embed<<<dim3(B_*N_), dim3(256), 0, stream>>>(x, emb, ws+XEMB);
  k_init<<<dim3((2*PER_+255)/256), dim3(256), 0, stream>>>(
      mW1in, mb1in, mW2in, mb2in, ws+PW1, ws+PB1, ws+PW2T, ws+PB2);
  k_coef<<<dim3(1), dim3(64), 0, stream>>>(ws+COEF);

  for (int s = 0; s < NSEG_; s++) {
    const float* segA = ws + XEMB + (size_t)s*SEG_*D_;
    // Q-proj (MFMA), l2n
    k_mf<0,0,0><<<dim3(8,1,B_), dim3(256), 0, stream>>>(
        segA, Wq, bq, ws+Q1, nullptr, SEG_, D_, D_, (long)N_*D_, 0, (long)SEG_*D_, 0, 0);
    k_l2n<<<dim3(B_*SEG_), dim3(256), 0, stream>>>(ws+Q1);
    // retrieve: AH = silu(Q1@W1+b1); HBUF = AH@W2+b2 (BT)
    k_mf<0,1,0><<<dim3(1,1,B_), dim3(256), 0, stream>>>(
        ws+Q1, ws+PW1, ws+PB1, ws+AH, nullptr, SEG_, W_, D_,
        (long)SEG_*D_, (long)D_*W_, (long)SEG_*W_, W_, 0);
    k_mf<1,0,0><<<dim3(8,1,B_), dim3(256), 0, stream>>>(
        ws+AH, ws+PW2T, ws+PB2, ws+HBUF, nullptr, SEG_, D_, W_,
        (long)SEG_*W_, (long)D_*W_, (long)SEG_*D_, D_, 0);
    // attention (concat fused into QKV GEMM)
    k_qkv_mfma<<<dim3(3*D_/128, (B_*T_+127)/128), dim3(256), 0, stream>>>(
        pers, ws+HBUF, ws+XEMB, s, aiw, aib, ws+QKV);
    k_attn<<<dim3(8, NH_, B_), dim3(256), 0, stream>>>(ws+QKV, ws+ATTN);
    k_mf<0,0,0><<<dim3(D_/128, 2, 1), dim3(256), 0, stream>>>(
        ws+ATTN, aow, aob, ws+SEGO, nullptr, B_*SEG_, D_, D_, 0, 0, 0, 0, 0);
    // fused K/V/Q projections of seg_out (MFMA), joint l2n
    k_gemmkvq_m<<<dim3(24, 2), dim3(256), 0, stream>>>(
        ws+SEGO, Wk, bk, Wv, bv, Wq, bq, ws+KM, ws+VM, ws+Q1);
    k_l2n2<<<dim3(2*B_*SEG_), dim3(256), 0, stream>>>(ws+KM, ws+Q1, B_*SEG_);
    // scan precompute: {Q1K, Q1Km} fused; G = K@K^T (MFMA BT)
    k_gemm2<<<dim3(2, 2, B_), dim3(256), 0, stream>>>(
        ws+KM, ws+PW1, ws+MW1, ws+AQ1K, ws+AQ1KM,
        D_, (long)SEG_*D_, (long)D_*W_, (long)SEG_*W_);
    k_mf<1,0,0><<<dim3(1,1,B_), dim3(256), 0, stream>>>(
        ws+KM, ws+KM, ws+ZEROB, ws+AGRAM, nullptr, SEG_, SEG_, D_,
        (long)SEG_*D_, (long)SEG_*D_, (long)SEG_*SEG_, 0, 0);
    // the scan (round-10 structure)
    k_scan<<<dim3(NB2_, B_), dim3(256), 0, stream>>>(
        ws+PW2T, ws+MW2T, ws+PB1, ws+MB1, ws+PB2, ws+MB2, ws+VM,
        ws+AQ1K, ws+AQ1KM, ws+AGRAM,
        ws+ADZ1, ws+AA1H, ws+AEH,
        ws+AEXR, ws+AEXEE,
        ws+COEF, (int*)(ws+CBAR), s);
    // reconstruct weights/momenta
    k_recon<<<dim3(32, 2, 4), dim3(256), 0, stream>>>(
        ws+PW1, ws+MW1, ws+PW2T, ws+MW2T,
        ws+KM, ws+AEH, ws+ADZ1, ws+AA1H, ws+COEF);
    // mem_out = mlp(p_new, Q1); OUTS = SEGO * mem_out (fused epilogue)
    k_mf<0,1,0><<<dim3(1,1,B_), dim3(256), 0, stream>>>(
        ws+Q1, ws+PW1, ws+PB1, ws+AH, nullptr, SEG_, W_, D_,
        (long)SEG_*D_, (long)D_*W_, (long)SEG_*W_, W_, 0);
    k_mf<1,0,1><<<dim3(8,1,B_), dim3(256), 0, stream>>>(
        ws+AH, ws+PW2T, ws+PB2, ws+OUTS + (size_t)s*SEG_*D_, ws+SEGO,
        SEG_, D_, W_, (long)SEG_*W_, (long)D_*W_, (long)N_*D_, D_, (long)SEG_*D_);
  }
  // head via bf16-split MFMA
  k_head_mfma<<<dim3(V_/128, (B_*N_)/128), dim3(256), 0, stream>>>(
      ws+OUTS, headw, headb, out, B_*N_, V_, D_);
}

// Round 13
// 7475.662 us; speedup vs baseline: 1.0271x; 1.0271x over previous
//
#include <hip/hip_runtime.h>
#include <math.h>

#define D_    1024
#define B_    2
#define N_    512
#define SEG_  128
#define NSEG_ 4
#define NPT_  16
#define T_    272
#define NH_   16
#define HD_   64
#define W_    128
#define V_    32000

#define THETA_ 0.1f
#define ETA_   0.9f
#define PDEC_  0.99f
#define EPSN_  1e-6f
#define NB2_  32
#define FSTR_ 32

typedef __bf16 bf16x8 __attribute__((ext_vector_type(8)));
typedef float  f32x4  __attribute__((ext_vector_type(4)));

// ---------------- workspace layout (float offsets) ----------------
static const size_t XEMB = 0;
static const size_t OUTS = XEMB + (size_t)B_*N_*D_;
static const size_t PW1  = OUTS + (size_t)B_*N_*D_;
static const size_t PB1  = PW1  + (size_t)B_*D_*W_;
static const size_t PW2T = PB1  + (size_t)B_*W_;
static const size_t PB2  = PW2T + (size_t)B_*D_*W_;
static const size_t MOM  = PB2  + (size_t)B_*D_;
static const size_t MW1  = MOM;
static const size_t MB1  = MW1  + (size_t)B_*D_*W_;
static const size_t MW2T = MB1  + (size_t)B_*W_;
static const size_t MB2  = MW2T + (size_t)B_*D_*W_;
static const size_t MOMSZ = (size_t)B_*(D_*W_ + W_ + D_*W_ + D_);
static const size_t Q1   = MOM  + MOMSZ;
static const size_t AH   = Q1   + (size_t)B_*SEG_*D_;
static const size_t HBUF = AH   + (size_t)B_*SEG_*W_;
static const size_t COMB = HBUF + (size_t)B_*SEG_*D_;
static const size_t QKV  = COMB + (size_t)B_*T_*D_;
static const size_t ATTN = QKV  + (size_t)B_*T_*3*D_;
static const size_t SEGO = ATTN + (size_t)B_*SEG_*D_;
static const size_t KM   = SEGO + (size_t)B_*SEG_*D_;
static const size_t VM   = KM   + (size_t)B_*SEG_*D_;
static const size_t MEMO = VM   + (size_t)B_*SEG_*D_;
static const size_t WSEND = MEMO + (size_t)B_*SEG_*D_;

// scan-phase buffers ALIAS the QKV region
static const size_t AQ1K  = QKV;
static const size_t AQ1KM = AQ1K  + 32768;
static const size_t AGRAM = AQ1KM + 32768;
static const size_t ADZ1  = AGRAM + 32768;
static const size_t AA1H  = ADZ1  + 32768;
static const size_t AEH   = AA1H  + 32768;
static const size_t AEXR  = AEH + (size_t)B_*SEG_*D_;
static const size_t AEXEE = AEXR + 16384;
// persistent tail
static const size_t COEF  = WSEND;
static const size_t ZEROB = COEF + 512;
static const size_t CBAR  = ZEROB + 128;

__device__ __forceinline__ float sigf(float x) { return 1.f/(1.f+expf(-x)); }

__device__ __forceinline__ void gstore(float* p, float v) {
  __hip_atomic_store(p, v, __ATOMIC_RELAXED, __HIP_MEMORY_SCOPE_AGENT);
}
__device__ __forceinline__ float gload(const float* p) {
  return __hip_atomic_load(p, __ATOMIC_RELAXED, __HIP_MEMORY_SCOPE_AGENT);
}

// RNE bf16 split: a ≈ float(h) + float(l)
__device__ __forceinline__ void bsplit(float a, short& h, short& l) {
  unsigned u = __builtin_bit_cast(unsigned, a);
  unsigned hb = (u + 0x7fffu + ((u >> 16) & 1u)) >> 16;
  h = (short)hb;
  float hf = __builtin_bit_cast(float, hb << 16);
  float r = a - hf;
  unsigned ur = __builtin_bit_cast(unsigned, r);
  unsigned lb = (ur + 0x7fffu + ((ur >> 16) & 1u)) >> 16;
  l = (short)lb;
}

// ---------------- fp32 64x64 GEMM (for tiny-grid ops: AH, Gram) ----------------
template<int BT, int SILU>
__global__ __launch_bounds__(256) void k_gemm(
    const float* __restrict__ A, const float* __restrict__ Bm,
    const float* __restrict__ bias, float* __restrict__ C,
    int M, int N, int K, long sA, long sB, long sC, long sBias)
{
  __shared__ float As[16][68];
  __shared__ float Bs[16][68];
  int bz = blockIdx.z;
  A += bz*sA; Bm += bz*sB; C += bz*sC; bias += bz*sBias;
  int n0 = blockIdx.x*64, m0 = blockIdx.y*64;
  int tid = threadIdx.x;
  int tx = tid & 15, ty = tid >> 4;
  int r  = tid >> 2;
  int kq = (tid & 3) * 4;
  float acc[4][4] = {};
  for (int k0 = 0; k0 < K; k0 += 16) {
    {
      int row = m0 + r;
      float4 v = make_float4(0.f,0.f,0.f,0.f);
      if (row < M) v = *(const float4*)(A + (long)row*K + k0 + kq);
      As[kq+0][r]=v.x; As[kq+1][r]=v.y; As[kq+2][r]=v.z; As[kq+3][r]=v.w;
    }
    if (BT) {
      int row = n0 + r;
      float4 v = *(const float4*)(Bm + (long)row*K + k0 + kq);
      Bs[kq+0][r]=v.x; Bs[kq+1][r]=v.y; Bs[kq+2][r]=v.z; Bs[kq+3][r]=v.w;
    } else {
      int c = tid & 63, r4 = tid >> 6;
      #pragma unroll
      for (int p = 0; p < 4; p++) {
        int kk = r4 + p*4;
        Bs[kk][c] = Bm[(long)(k0+kk)*N + n0 + c];
      }
    }
    __syncthreads();
    #pragma unroll
    for (int kk = 0; kk < 16; kk++) {
      float av[4], bv[4];
      #pragma unroll
      for (int i=0;i<4;i++) av[i] = As[kk][ty*4+i];
      #pragma unroll
      for (int j=0;j<4;j++) bv[j] = Bs[kk][tx*4+j];
      #pragma unroll
      for (int i=0;i<4;i++)
        #pragma unroll
        for (int j=0;j<4;j++)
          acc[i][j] = fmaf(av[i], bv[j], acc[i][j]);
    }
    __syncthreads();
  }
  #pragma unroll
  for (int i=0;i<4;i++) {
    int row = m0 + ty*4 + i;
    if (row >= M) continue;
    #pragma unroll
    for (int j=0;j<4;j++) {
      int col = n0 + tx*4 + j;
      float v = acc[i][j] + bias[col];
      if (SILU) v = v * sigf(v);
      C[(long)row*N + col] = v;
    }
  }
}

// ------- universal bf16-split MFMA GEMM (large-grid ops only) -------
template<int BT, int SILU, int MUL>
__global__ __launch_bounds__(256) void k_mf(
    const float* __restrict__ A, const float* __restrict__ Bm,
    const float* __restrict__ bias, float* __restrict__ C,
    const float* __restrict__ aux,
    int M, int N, int K, long sA, long sB, long sC, long sBias, long sAux)
{
  __shared__ short Ah[128][48];
  __shared__ short Al[128][48];
  __shared__ short Bh[32][132];
  __shared__ short Bl[32][132];
  int bz = blockIdx.z;
  A += bz*sA; Bm += bz*sB; C += bz*sC; bias += bz*sBias;
  if (MUL) aux += bz*sAux;
  int n0 = blockIdx.x*128, m0 = blockIdx.y*128;
  int tid = threadIdx.x;
  int wave = tid >> 6, lane = tid & 63;
  int wm = (wave >> 1) * 64, wn = (wave & 1) * 64;
  int lrow = lane & 15, lk = (lane >> 4) * 8;
  int arow0 = min(m0 + (tid >> 1), M-1);
  f32x4 acc[4][4] = {};
  for (int k0 = 0; k0 < K; k0 += 32) {
    __syncthreads();
    {
      int r = tid >> 1, kq = (tid & 1) * 16;
      const float* ap = A + (long)arow0*K + k0 + kq;
      #pragma unroll
      for (int q = 0; q < 16; q += 4) {
        float4 v = *(const float4*)(ap + q);
        short h0,l0,h1,l1,h2,l2,h3,l3;
        bsplit(v.x,h0,l0); bsplit(v.y,h1,l1); bsplit(v.z,h2,l2); bsplit(v.w,h3,l3);
        *(short4*)&Ah[r][kq+q] = make_short4(h0,h1,h2,h3);
        *(short4*)&Al[r][kq+q] = make_short4(l0,l1,l2,l3);
      }
    }
    if (BT) {
      int nn = tid >> 1, kq2 = (tid & 1) * 16;
      const float* bp = Bm + (long)(n0+nn)*K + k0 + kq2;
      #pragma unroll
      for (int q = 0; q < 16; q += 4) {
        float4 v = *(const float4*)(bp + q);
        short h0,l0,h1,l1,h2,l2,h3,l3;
        bsplit(v.x,h0,l0); bsplit(v.y,h1,l1); bsplit(v.z,h2,l2); bsplit(v.w,h3,l3);
        Bh[kq2+q+0][nn]=h0; Bh[kq2+q+1][nn]=h1; Bh[kq2+q+2][nn]=h2; Bh[kq2+q+3][nn]=h3;
        Bl[kq2+q+0][nn]=l0; Bl[kq2+q+1][nn]=l1; Bl[kq2+q+2][nn]=l2; Bl[kq2+q+3][nn]=l3;
      }
    } else {
      int kr = tid >> 3, nq = (tid & 7) * 16;
      const float* bp = Bm + (long)(k0 + kr)*N + n0 + nq;
      #pragma unroll
      for (int q = 0; q < 16; q += 4) {
        float4 v = *(const float4*)(bp + q);
        short h0,l0,h1,l1,h2,l2,h3,l3;
        bsplit(v.x,h0,l0); bsplit(v.y,h1,l1); bsplit(v.z,h2,l2); bsplit(v.w,h3,l3);
        *(short4*)&Bh[kr][nq+q] = make_short4(h0,h1,h2,h3);
        *(short4*)&Bl[kr][nq+q] = make_short4(l0,l1,l2,l3);
      }
    }
    __syncthreads();
    bf16x8 bh[4], bl[4];
    #pragma unroll
    for (int nf = 0; nf < 4; nf++) {
      int col = wn + nf*16 + lrow;
      #pragma unroll
      for (int j = 0; j < 8; j++) {
        bh[nf][j] = __builtin_bit_cast(__bf16, Bh[lk+j][col]);
        bl[nf][j] = __builtin_bit_cast(__bf16, Bl[lk+j][col]);
      }
    }
    #pragma unroll
    for (int mf = 0; mf < 4; mf++) {
      int ar2 = wm + mf*16 + lrow;
      bf16x8 ah = *(const bf16x8*)&Ah[ar2][lk];
      bf16x8 al = *(const bf16x8*)&Al[ar2][lk];
      #pragma unroll
      for (int nf = 0; nf < 4; nf++) {
        acc[mf][nf] = __builtin_amdgcn_mfma_f32_16x16x32_bf16(ah, bh[nf], acc[mf][nf], 0, 0, 0);
        acc[mf][nf] = __builtin_amdgcn_mfma_f32_16x16x32_bf16(ah, bl[nf], acc[mf][nf], 0, 0, 0);
        acc[mf][nf] = __builtin_amdgcn_mfma_f32_16x16x32_bf16(al, bh[nf], acc[mf][nf], 0, 0, 0);
      }
    }
  }
  #pragma unroll
  for (int mf = 0; mf < 4; mf++) {
    #pragma unroll
    for (int nf = 0; nf < 4; nf++) {
      int col = n0 + wn + nf*16 + lrow;
      float bv = bias[col];
      #pragma unroll
      for (int j = 0; j < 4; j++) {
        int row = m0 + wm + mf*16 + (lane >> 4)*4 + j;
        if (row < M) {
          float v = acc[mf][nf][j] + bv;
          if (SILU) v = v * sigf(v);
          if (MUL)  v *= aux[(long)row*N + col];
          C[(long)row*N + col] = v;
        }
      }
    }
  }
}

// ------- dual-output 64x64 fp32 GEMM: C1=A@B1, C2=A@B2 (no bias) ----
__global__ __launch_bounds__(256) void k_gemm2(
    const float* __restrict__ A, const float* __restrict__ B1,
    const float* __restrict__ B2, float* __restrict__ C1, float* __restrict__ C2,
    int K, long sA, long sB, long sC)
{
  __shared__ float As[16][68];
  __shared__ float B1s[16][68];
  __shared__ float B2s[16][68];
  int bz = blockIdx.z;
  A += bz*sA; B1 += bz*sB; B2 += bz*sB; C1 += bz*sC; C2 += bz*sC;
  int n0 = blockIdx.x*64, m0 = blockIdx.y*64;
  int tid = threadIdx.x;
  int tx = tid & 15, ty = tid >> 4;
  int r  = tid >> 2;
  int kq = (tid & 3) * 4;
  float acc1[4][4] = {}, acc2[4][4] = {};
  for (int k0 = 0; k0 < K; k0 += 16) {
    {
      float4 v = *(const float4*)(A + (long)(m0+r)*K + k0 + kq);
      As[kq+0][r]=v.x; As[kq+1][r]=v.y; As[kq+2][r]=v.z; As[kq+3][r]=v.w;
    }
    {
      int c = tid & 63, r4 = tid >> 6;
      #pragma unroll
      for (int p = 0; p < 4; p++) {
        int kk = r4 + p*4;
        B1s[kk][c] = B1[(long)(k0+kk)*W_ + n0 + c];
        B2s[kk][c] = B2[(long)(k0+kk)*W_ + n0 + c];
      }
    }
    __syncthreads();
    #pragma unroll
    for (int kk = 0; kk < 16; kk++) {
      float av[4], b1v[4], b2v[4];
      #pragma unroll
      for (int i=0;i<4;i++) av[i] = As[kk][ty*4+i];
      #pragma unroll
      for (int j=0;j<4;j++) { b1v[j] = B1s[kk][tx*4+j]; b2v[j] = B2s[kk][tx*4+j]; }
      #pragma unroll
      for (int i=0;i<4;i++)
        #pragma unroll
        for (int j=0;j<4;j++) {
          acc1[i][j] = fmaf(av[i], b1v[j], acc1[i][j]);
          acc2[i][j] = fmaf(av[i], b2v[j], acc2[i][j]);
        }
    }
    __syncthreads();
  }
  #pragma unroll
  for (int i=0;i<4;i++) {
    int row = m0 + ty*4 + i;
    #pragma unroll
    for (int j=0;j<4;j++) {
      int col = n0 + tx*4 + j;
      C1[(long)row*W_ + col] = acc1[i][j];
      C2[(long)row*W_ + col] = acc2[i][j];
    }
  }
}

// ------- QKV MFMA GEMM with fused concat -------
__global__ __launch_bounds__(256) void k_qkv_mfma(
    const float* __restrict__ pers, const float* __restrict__ hbuf,
    const float* __restrict__ xemb, int s,
    const float* __restrict__ Bm, const float* __restrict__ bias,
    float* __restrict__ C)
{
  __shared__ short Ah[128][48];
  __shared__ short Al[128][48];
  __shared__ short Bh[32][132];
  __shared__ short Bl[32][132];
  const int M = B_*T_, N = 3*D_, K = D_;
  int n0 = blockIdx.x*128, m0 = blockIdx.y*128;
  int tid = threadIdx.x;
  int wave = tid >> 6, lane = tid & 63;
  int wm = (wave >> 1) * 64, wn = (wave & 1) * 64;
  int lrow = lane & 15, lk = (lane >> 4) * 8;
  int grow = min(m0 + (tid >> 1), M-1);
  int b = grow >= T_ ? 1 : 0;
  int rt = grow - b*T_;
  const float* asrc;
  if (rt < NPT_)            asrc = pers + (long)rt*D_;
  else if (rt < NPT_+SEG_)  asrc = hbuf + ((long)b*SEG_ + (rt-NPT_))*D_;
  else                      asrc = xemb + ((long)b*N_ + s*SEG_ + (rt-NPT_-SEG_))*D_;
  f32x4 acc[4][4] = {};
  for (int k0 = 0; k0 < K; k0 += 32) {
    __syncthreads();
    {
      int r = tid >> 1, kq = (tid & 1) * 16;
      const float* ap = asrc + k0 + kq;
      #pragma unroll
      for (int q = 0; q < 16; q += 4) {
        float4 v = *(const float4*)(ap + q);
        short h0,l0,h1,l1,h2,l2,h3,l3;
        bsplit(v.x,h0,l0); bsplit(v.y,h1,l1); bsplit(v.z,h2,l2); bsplit(v.w,h3,l3);
        *(short4*)&Ah[r][kq+q] = make_short4(h0,h1,h2,h3);
        *(short4*)&Al[r][kq+q] = make_short4(l0,l1,l2,l3);
      }
    }
    {
      int kr = tid >> 3, nq = (tid & 7) * 16;
      const float* bp = Bm + (long)(k0 + kr)*N + n0 + nq;
      #pragma unroll
      for (int q = 0; q < 16; q += 4) {
        float4 v = *(const float4*)(bp + q);
        short h0,l0,h1,l1,h2,l2,h3,l3;
        bsplit(v.x,h0,l0); bsplit(v.y,h1,l1); bsplit(v.z,h2,l2); bsplit(v.w,h3,l3);
        *(short4*)&Bh[kr][nq+q] = make_short4(h0,h1,h2,h3);
        *(short4*)&Bl[kr][nq+q] = make_short4(l0,l1,l2,l3);
      }
    }
    __syncthreads();
    bf16x8 bh[4], bl[4];
    #pragma unroll
    for (int nf = 0; nf < 4; nf++) {
      int col = wn + nf*16 + lrow;
      #pragma unroll
      for (int j = 0; j < 8; j++) {
        bh[nf][j] = __builtin_bit_cast(__bf16, Bh[lk+j][col]);
        bl[nf][j] = __builtin_bit_cast(__bf16, Bl[lk+j][col]);
      }
    }
    #pragma unroll
    for (int mf = 0; mf < 4; mf++) {
      int ar2 = wm + mf*16 + lrow;
      bf16x8 ah = *(const bf16x8*)&Ah[ar2][lk];
      bf16x8 al = *(const bf16x8*)&Al[ar2][lk];
      #pragma unroll
      for (int nf = 0; nf < 4; nf++) {
        acc[mf][nf] = __builtin_amdgcn_mfma_f32_16x16x32_bf16(ah, bh[nf], acc[mf][nf], 0, 0, 0);
        acc[mf][nf] = __builtin_amdgcn_mfma_f32_16x16x32_bf16(ah, bl[nf], acc[mf][nf], 0, 0, 0);
        acc[mf][nf] = __builtin_amdgcn_mfma_f32_16x16x32_bf16(al, bh[nf], acc[mf][nf], 0, 0, 0);
      }
    }
  }
  #pragma unroll
  for (int mf = 0; mf < 4; mf++) {
    #pragma unroll
    for (int nf = 0; nf < 4; nf++) {
      int col = n0 + wn + nf*16 + lrow;
      float bv = bias[col];
      #pragma unroll
      for (int j = 0; j < 4; j++) {
        int row = m0 + wm + mf*16 + (lane >> 4)*4 + j;
        if (row < M) C[(long)row*N + col] = acc[mf][nf][j] + bv;
      }
    }
  }
}

// ------- fused K/V/Q projection via bf16-split MFMA ----
__global__ __launch_bounds__(256) void k_gemmkvq_m(
    const float* __restrict__ A,
    const float* __restrict__ Wk, const float* __restrict__ bk,
    const float* __restrict__ Wv, const float* __restrict__ bv,
    const float* __restrict__ Wq, const float* __restrict__ bq,
    float* __restrict__ KMo, float* __restrict__ VMo, float* __restrict__ Q1o)
{
  __shared__ short Ah[128][48];
  __shared__ short Al[128][48];
  __shared__ short Bh[32][132];
  __shared__ short Bl[32][132];
  int bx = blockIdx.x;
  int sel = bx >> 3;
  int n0 = (bx & 7) * 128;
  int m0 = blockIdx.y * 128;
  const float* Bm   = sel == 0 ? Wk : sel == 1 ? Wv : Wq;
  const float* bias = sel == 0 ? bk : sel == 1 ? bv : bq;
  float* C          = sel == 0 ? KMo : sel == 1 ? VMo : Q1o;
  int tid = threadIdx.x;
  int wave = tid >> 6, lane = tid & 63;
  int wm = (wave >> 1) * 64, wn = (wave & 1) * 64;
  int lrow = lane & 15, lk = (lane >> 4) * 8;
  f32x4 acc[4][4] = {};
  for (int k0 = 0; k0 < D_; k0 += 32) {
    __syncthreads();
    {
      int r = tid >> 1, kq = (tid & 1) * 16;
      const float* ap = A + (long)(m0 + r)*D_ + k0 + kq;
      #pragma unroll
      for (int q = 0; q < 16; q += 4) {
        float4 v = *(const float4*)(ap + q);
        short h0,l0,h1,l1,h2,l2,h3,l3;
        bsplit(v.x,h0,l0); bsplit(v.y,h1,l1); bsplit(v.z,h2,l2); bsplit(v.w,h3,l3);
        *(short4*)&Ah[r][kq+q] = make_short4(h0,h1,h2,h3);
        *(short4*)&Al[r][kq+q] = make_short4(l0,l1,l2,l3);
      }
    }
    {
      int kr = tid >> 3, nq = (tid & 7) * 16;
      const float* bp = Bm + (long)(k0 + kr)*D_ + n0 + nq;
      #pragma unroll
      for (int q = 0; q < 16; q += 4) {
        float4 v = *(const float4*)(bp + q);
        short h0,l0,h1,l1,h2,l2,h3,l3;
        bsplit(v.x,h0,l0); bsplit(v.y,h1,l1); bsplit(v.z,h2,l2); bsplit(v.w,h3,l3);
        *(short4*)&Bh[kr][nq+q] = make_short4(h0,h1,h2,h3);
        *(short4*)&Bl[kr][nq+q] = make_short4(l0,l1,l2,l3);
      }
    }
    __syncthreads();
    bf16x8 bh[4], bl[4];
    #pragma unroll
    for (int nf = 0; nf < 4; nf++) {
      int col = wn + nf*16 + lrow;
      #pragma unroll
      for (int j = 0; j < 8; j++) {
        bh[nf][j] = __builtin_bit_cast(__bf16, Bh[lk+j][col]);
        bl[nf][j] = __builtin_bit_cast(__bf16, Bl[lk+j][col]);
      }
    }
    #pragma unroll
    for (int mf = 0; mf < 4; mf++) {
      int ar2 = wm + mf*16 + lrow;
      bf16x8 ah = *(const bf16x8*)&Ah[ar2][lk];
      bf16x8 al = *(const bf16x8*)&Al[ar2][lk];
      #pragma unroll
      for (int nf = 0; nf < 4; nf++) {
        acc[mf][nf] = __builtin_amdgcn_mfma_f32_16x16x32_bf16(ah, bh[nf], acc[mf][nf], 0, 0, 0);
        acc[mf][nf] = __builtin_amdgcn_mfma_f32_16x16x32_bf16(ah, bl[nf], acc[mf][nf], 0, 0, 0);
        acc[mf][nf] = __builtin_amdgcn_mfma_f32_16x16x32_bf16(al, bh[nf], acc[mf][nf], 0, 0, 0);
      }
    }
  }
  #pragma unroll
  for (int mf = 0; mf < 4; mf++) {
    #pragma unroll
    for (int nf = 0; nf < 4; nf++) {
      int col = n0 + wn + nf*16 + lrow;
      float bvx = bias[col];
      #pragma unroll
      for (int j = 0; j < 4; j++) {
        int row = m0 + wm + mf*16 + (lane >> 4)*4 + j;
        C[(long)row*D_ + col] = acc[mf][nf][j] + bvx;
      }
    }
  }
}

// ------- head GEMM via bf16-split MFMA -------
__global__ __launch_bounds__(256) void k_head_mfma(
    const float* __restrict__ A, const float* __restrict__ Bm,
    const float* __restrict__ bias, float* __restrict__ C,
    int M, int N, int K)
{
  __shared__ short Ah[128][48];
  __shared__ short Al[128][48];
  __shared__ short Bh[32][132];
  __shared__ short Bl[32][132];
  int n0 = blockIdx.x*128, m0 = blockIdx.y*128;
  int tid = threadIdx.x;
  int wave = tid >> 6, lane = tid & 63;
  int wm = (wave >> 1) * 64, wn = (wave & 1) * 64;
  int lrow = lane & 15, lk = (lane >> 4) * 8;
  f32x4 acc[4][4] = {};
  for (int k0 = 0; k0 < K; k0 += 32) {
    __syncthreads();
    {
      int r = tid >> 1, kq = (tid & 1) * 16;
      const float* ap = A + (long)(m0 + r)*K + k0 + kq;
      #pragma unroll
      for (int q = 0; q < 16; q += 4) {
        float4 v = *(const float4*)(ap + q);
        short h0,l0,h1,l1,h2,l2,h3,l3;
        bsplit(v.x,h0,l0); bsplit(v.y,h1,l1); bsplit(v.z,h2,l2); bsplit(v.w,h3,l3);
        *(short4*)&Ah[r][kq+q] = make_short4(h0,h1,h2,h3);
        *(short4*)&Al[r][kq+q] = make_short4(l0,l1,l2,l3);
      }
    }
    {
      int kr = tid >> 3, nq = (tid & 7) * 16;
      const float* bp = Bm + (long)(k0 + kr)*N + n0 + nq;
      #pragma unroll
      for (int q = 0; q < 16; q += 4) {
        float4 v = *(const float4*)(bp + q);
        short h0,l0,h1,l1,h2,l2,h3,l3;
        bsplit(v.x,h0,l0); bsplit(v.y,h1,l1); bsplit(v.z,h2,l2); bsplit(v.w,h3,l3);
        *(short4*)&Bh[kr][nq+q] = make_short4(h0,h1,h2,h3);
        *(short4*)&Bl[kr][nq+q] = make_short4(l0,l1,l2,l3);
      }
    }
    __syncthreads();
    bf16x8 bh[4], bl[4];
    #pragma unroll
    for (int nf = 0; nf < 4; nf++) {
      int col = wn + nf*16 + lrow;
      #pragma unroll
      for (int j = 0; j < 8; j++) {
        bh[nf][j] = __builtin_bit_cast(__bf16, Bh[lk+j][col]);
        bl[nf][j] = __builtin_bit_cast(__bf16, Bl[lk+j][col]);
      }
    }
    #pragma unroll
    for (int mf = 0; mf < 4; mf++) {
      int arow2 = wm + mf*16 + lrow;
      bf16x8 ah = *(const bf16x8*)&Ah[arow2][lk];
      bf16x8 al = *(const bf16x8*)&Al[arow2][lk];
      #pragma unroll
      for (int nf = 0; nf < 4; nf++) {
        acc[mf][nf] = __builtin_amdgcn_mfma_f32_16x16x32_bf16(ah, bh[nf], acc[mf][nf], 0, 0, 0);
        acc[mf][nf] = __builtin_amdgcn_mfma_f32_16x16x32_bf16(ah, bl[nf], acc[mf][nf], 0, 0, 0);
        acc[mf][nf] = __builtin_amdgcn_mfma_f32_16x16x32_bf16(al, bh[nf], acc[mf][nf], 0, 0, 0);
      }
    }
  }
  #pragma unroll
  for (int mf = 0; mf < 4; mf++) {
    #pragma unroll
    for (int nf = 0; nf < 4; nf++) {
      int col = n0 + wn + nf*16 + lrow;
      float bv = bias[col];
      #pragma unroll
      for (int j = 0; j < 4; j++) {
        int row = m0 + wm + mf*16 + (lane >> 4)*4 + j;
        C[(long)row*N + col] = acc[mf][nf][j] + bv;
      }
    }
  }
}

// ---------------- small kernels ----------------
__global__ void k_embed(const int* __restrict__ x, const float* __restrict__ emb,
                        float* __restrict__ xe)
{
  int row = blockIdx.x, tid = threadIdx.x;
  int idx = x[row];
  float4 v = *(const float4*)(emb + (long)idx*D_ + tid*4);
  *(float4*)(xe + (long)row*D_ + tid*4) = v;
}

#define PER_ 263296L
__global__ void k_init(const float* __restrict__ mW1in, const float* __restrict__ mb1in,
                       const float* __restrict__ mW2in, const float* __restrict__ mb2in,
                       float* __restrict__ pW1, float* __restrict__ pb1,
                       float* __restrict__ pW2T, float* __restrict__ pb2)
{
  long g = (long)blockIdx.x*256 + threadIdx.x;
  if (g >= 2*PER_) return;
  int b = (int)(g / PER_);
  long rr = g % PER_;
  if (rr < 131072)       pW1[(long)b*131072 + rr] = mW1in[rr];
  else if (rr < 131200)  pb1[b*W_ + (rr-131072)] = mb1in[rr-131072];
  else if (rr < 262272) { long l = rr-131200; int j=(int)(l>>7), h=(int)(l&127);
                          pW2T[(long)b*131072 + l] = mW2in[(long)h*D_ + j]; }
  else                   pb2[b*D_ + (rr-262272)] = mb2in[rr-262272];
}

__global__ void k_coef(float* __restrict__ c)
{
  if (blockIdx.x == 0 && threadIdx.x == 0) {
    c[0] = 1.f; c[128] = 1.f;
    float A = 1.f, eta_d = 1.f;
    for (int d = 1; d < 128; d++) {
      eta_d *= ETA_;
      A = PDEC_*A + eta_d;
      c[d] = A;
      c[128 + d] = eta_d;
    }
    c[256] = 1.f;
    float bp = 1.f;
    for (int t = 1; t <= 128; t++) { bp *= PDEC_; c[256 + t] = bp; }
  }
}

__global__ __launch_bounds__(256) void k_l2n(float* __restrict__ X)
{
  long row = blockIdx.x;
  float* p = X + row*D_;
  int tid = threadIdx.x;
  float4 v = *(float4*)(p + tid*4);
  float ss = v.x*v.x + v.y*v.y + v.z*v.z + v.w*v.w;
  for (int o=32;o;o>>=1) ss += __shfl_xor(ss,o);
  __shared__ float wsum[4];
  if ((tid&63)==0) wsum[tid>>6] = ss;
  __syncthreads();
  float tot = wsum[0]+wsum[1]+wsum[2]+wsum[3];
  float sc = 1.f/(sqrtf(tot)+EPSN_);
  v.x*=sc; v.y*=sc; v.z*=sc; v.w*=sc;
  *(float4*)(p + tid*4) = v;
}

// dual-array l2n: rows [0,R) from X1, rows [R,2R) from X2
__global__ __launch_bounds__(256) void k_l2n2(float* __restrict__ X1, float* __restrict__ X2, int R)
{
  int row = blockIdx.x;
  float* p = (row < R ? X1 + (long)row*D_ : X2 + (long)(row-R)*D_);
  int tid = threadIdx.x;
  float4 v = *(float4*)(p + tid*4);
  float ss = v.x*v.x + v.y*v.y + v.z*v.z + v.w*v.w;
  for (int o=32;o;o>>=1) ss += __shfl_xor(ss,o);
  __shared__ float wsum[4];
  if ((tid&63)==0) wsum[tid>>6] = ss;
  __syncthreads();
  float tot = wsum[0]+wsum[1]+wsum[2]+wsum[3];
  float sc = 1.f/(sqrtf(tot)+EPSN_);
  v.x*=sc; v.y*=sc; v.z*=sc; v.w*=sc;
  *(float4*)(p + tid*4) = v;
}

__global__ __launch_bounds__(256) void k_attn(const float* __restrict__ qkv,
                                              float* __restrict__ outp)
{
  __shared__ float sQ[16][68];
  __shared__ float sKV[64][68];
  __shared__ float sS[16][273];
  int qt = blockIdx.x, head = blockIdx.y, b = blockIdx.z;
  int tid = threadIdx.x;
  const float* base = qkv + (long)b*T_*3*D_;
  int qoff = head*HD_, koff = D_ + head*HD_, voff = 2*D_ + head*HD_;
  int qrow0 = NPT_ + SEG_ + qt*16;
  {
    int rr = tid>>4, c4 = (tid&15)*4;
    float4 v = *(const float4*)(base + (long)(qrow0+rr)*3*D_ + qoff + c4);
    sQ[rr][c4]=v.x; sQ[rr][c4+1]=v.y; sQ[rr][c4+2]=v.z; sQ[rr][c4+3]=v.w;
  }
  __syncthreads();
  for (int j0 = 0; j0 < T_; j0 += 64) {
    int chunk = min(64, T_ - j0);
    {
      int jj = tid>>2, cq = (tid&3)*16;
      if (jj < chunk) {
        #pragma unroll
        for (int q4=0;q4<4;q4++) {
          float4 v = *(const float4*)(base + (long)(j0+jj)*3*D_ + koff + cq + q4*4);
          sKV[jj][cq+q4*4]=v.x; sKV[jj][cq+q4*4+1]=v.y; sKV[jj][cq+q4*4+2]=v.z; sKV[jj][cq+q4*4+3]=v.w;
        }
      }
    }
    __syncthreads();
    int rr = tid>>4, jj0 = tid&15;
    #pragma unroll
    for (int p=0;p<4;p++) {
      int jj = jj0 + p*16;
      if (jj < chunk) {
        float s = 0.f;
        #pragma unroll 8
        for (int c=0;c<HD_;c++) s = fmaf(sQ[rr][c], sKV[jj][c], s);
        s *= 0.125f;
        int jg = j0 + jj, qg = qrow0 + rr;
        if (jg > qg) s = -3.0e38f;
        sS[rr][jg] = s;
      }
    }
    __syncthreads();
  }
  {
    int rr = tid>>4, l16 = tid&15;
    float m = -3.4e38f;
    for (int j=l16; j<T_; j+=16) m = fmaxf(m, sS[rr][j]);
    for (int o=8;o;o>>=1) m = fmaxf(m, __shfl_xor(m,o));
    float sum = 0.f;
    for (int j=l16; j<T_; j+=16) { float e = expf(sS[rr][j]-m); sS[rr][j] = e; sum += e; }
    for (int o=8;o;o>>=1) sum += __shfl_xor(sum,o);
    float inv = 1.f/sum;
    for (int j=l16; j<T_; j+=16) sS[rr][j] *= inv;
  }
  __syncthreads();
  float acc[4] = {0.f,0.f,0.f,0.f};
  int rr = tid>>4, c4 = (tid&15)*4;
  for (int j0 = 0; j0 < T_; j0 += 64) {
    int chunk = min(64, T_ - j0);
    {
      int jj = tid>>2, cq = (tid&3)*16;
      if (jj < chunk) {
        #pragma unroll
        for (int q4=0;q4<4;q4++) {
          float4 v = *(const float4*)(base + (long)(j0+jj)*3*D_ + voff + cq + q4*4);
          sKV[jj][cq+q4*4]=v.x; sKV[jj][cq+q4*4+1]=v.y; sKV[jj][cq+q4*4+2]=v.z; sKV[jj][cq+q4*4+3]=v.w;
        }
      }
    }
    __syncthreads();
    for (int jj=0; jj<chunk; jj++) {
      float p = sS[rr][j0+jj];
      #pragma unroll
      for (int i=0;i<4;i++) acc[i] = fmaf(p, sKV[jj][c4+i], acc[i]);
    }
    __syncthreads();
  }
  float4 o4 = make_float4(acc[0],acc[1],acc[2],acc[3]);
  *(float4*)(outp + ((long)(b*SEG_) + qt*16 + rr)*D_ + head*HD_ + c4) = o4;
}

// ------- fence-free flag barrier ---------
__device__ __forceinline__ void gbar(int* flags, int blk, int gen)
{
  asm volatile("s_waitcnt vmcnt(0) lgkmcnt(0)" ::: "memory");
  __syncthreads();
  if (threadIdx.x == 0)
    __hip_atomic_store(flags + blk*FSTR_, gen, __ATOMIC_RELAXED, __HIP_MEMORY_SCOPE_AGENT);
  if (threadIdx.x < NB2_) {
    while (__hip_atomic_load(flags + threadIdx.x*FSTR_, __ATOMIC_RELAXED,
                             __HIP_MEMORY_SCOPE_AGENT) < gen)
      __builtin_amdgcn_s_sleep(1);
  }
  __syncthreads();
}

// ---- persistent token-space scan (round-10 version: reg-W, 1 barrier) ----
__global__ __launch_bounds__(256) void k_scan(
  const float* __restrict__ pW2T, const float* __restrict__ mW2T,
  float* __restrict__ pb1, float* __restrict__ mb1,
  float* __restrict__ pb2, float* __restrict__ mb2,
  const float* __restrict__ Vm,
  const float* __restrict__ q1k, const float* __restrict__ q1km,
  const float* __restrict__ G,
  float* __restrict__ dz1o, float* __restrict__ a1o, float* __restrict__ eo,
  float* __restrict__ exR, float* __restrict__ exEE,
  const float* __restrict__ coef, int* __restrict__ barbase, int seg)
{
  __shared__ float sDZ[128][129];
  __shared__ float sA1[128][129];
  __shared__ float sEh[128][33];
  __shared__ float sB1[128], sMB1[128], sZ1[128], sR[128];
  __shared__ float sB2[32], sMB2[32];
  __shared__ float sAt[128];
  __shared__ float sBp[129];
  __shared__ float sGc[128];
  __shared__ float sS[128];
  __shared__ float sEEc[128];

  int b = blockIdx.y, blk = blockIdx.x, tid = threadIdx.x;
  int j0 = blk*32;
  int* flags = barbase + b*(NB2_*FSTR_);
  int gbase = seg*200;
  const float* W0 = pW2T + (long)b*131072;
  const float* Wm = mW2T + (long)b*131072;

  int jD = tid >> 3, lD = tid & 7;
  float rD0[16], rDm[16];
  #pragma unroll
  for (int k = 0; k < 16; k++) {
    rD0[k] = W0[(long)(j0+jD)*128 + lD + 8*k];
    rDm[k] = Wm[(long)(j0+jD)*128 + lD + 8*k];
  }
  int hE = tid >> 1, halfE = tid & 1;
  float rE0[16], rEm[16];
  #pragma unroll
  for (int q = 0; q < 16; q++) {
    rE0[q] = W0[(long)(j0 + halfE*16 + q)*128 + hE];
    rEm[q] = Wm[(long)(j0 + halfE*16 + q)*128 + hE];
  }

  if (tid < 128) { sAt[tid] = coef[tid]; sB1[tid] = pb1[b*W_+tid]; sMB1[tid] = mb1[b*W_+tid]; }
  else if (tid < 160) { int j = tid-128; sB2[j] = pb2[b*D_+j0+j]; sMB2[j] = mb2[b*D_+j0+j]; }
  for (int i = tid; i < 129; i += 256) sBp[i] = coef[256+i];
  __syncthreads();

  for (int t = 0; t < SEG_; ++t) {
    int par = t & 1;
    float bp = sBp[t];
    float ca = (t>0) ? ETA_*sAt[t-1] : 0.f;

    float rq1k = 0.f, rq1km = 0.f;
    if (tid < 128) {
      rq1k  = q1k [((long)b*SEG_+t)*W_ + tid];
      rq1km = q1km[((long)b*SEG_+t)*W_ + tid];
      if (t > 0) {
        float mm = ETA_*sMB1[tid] - THETA_*sDZ[t-1][tid];
        sMB1[tid] = mm; sB1[tid] = PDEC_*sB1[tid] + mm;
      }
      if (tid < t) sGc[tid] = sAt[t-1-tid]*G[((long)b*SEG_+t)*SEG_ + tid];
    } else if (tid < 160) {
      int j = tid-128;
      if (t > 0) {
        float mm = ETA_*sMB2[j] - 2.f*THETA_*sEh[t-1][j];
        sMB2[j] = mm; sB2[j] = PDEC_*sB2[j] + mm;
      }
    }
    __syncthreads();

    if (tid < 128) {
      float acc = 0.f;
      for (int u = 0; u < t; ++u) acc = fmaf(sGc[u], sDZ[u][tid], acc);
      float z1 = bp*rq1k + ca*rq1km + sB1[tid] - THETA_*acc;
      sZ1[tid] = z1;
      sA1[t][tid] = z1 * sigf(z1);
    }
    __syncthreads();

    if (tid < t) {
      float acc = 0.f;
      #pragma unroll 8
      for (int h = 0; h < 128; ++h) acc = fmaf(sA1[tid][h], sA1[t][h], acc);
      sS[tid] = -2.f*THETA_*sAt[t-1-tid]*acc;
    }
    __syncthreads();

    {
      float g = 0.f, gm = 0.f;
      #pragma unroll
      for (int k = 0; k < 16; k++) {
        float a = sA1[t][lD + 8*k];
        g  = fmaf(rD0[k], a, g);
        gm = fmaf(rDm[k], a, gm);
      }
      float corr = 0.f;
      for (int u = lD; u < t; u += 8) corr = fmaf(sS[u], sEh[u][jD], corr);
      float tot = bp*g + ca*gm + corr;
      tot += __shfl_xor(tot,4); tot += __shfl_xor(tot,2); tot += __shfl_xor(tot,1);
      if (lD == 0) sEh[t][jD] = tot + sB2[jD] - Vm[((long)b*SEG_+t)*D_ + j0+jD];
    }
    __syncthreads();

    {
      float racc = 0.f;
      #pragma unroll
      for (int q = 0; q < 16; ++q) {
        float w = bp*rE0[q] + ca*rEm[q];
        racc = fmaf(w, sEh[t][halfE*16 + q], racc);
      }
      racc += __shfl_xor(racc,1);
      if (halfE == 0) gstore(&exR[(((long)par*B_ + b)*NB2_ + blk)*W_ + hE], racc);
      if (hE < t) {
        float eacc = 0.f;
        #pragma unroll
        for (int q = 0; q < 16; ++q)
          eacc = fmaf(sEh[hE][halfE*16 + q], sEh[t][halfE*16 + q], eacc);
        eacc += __shfl_xor(eacc,1);
        if (halfE == 0) gstore(&exEE[(((long)par*B_ + b)*NB2_ + blk)*W_ + hE], eacc);
      }
    }
    gbar(flags, blk, gbase + t + 1);

    {
      float racc = 0.f;
      #pragma unroll
      for (int k = 0; k < 16; ++k)
        racc += gload(&exR[(((long)par*B_ + b)*NB2_ + halfE*16 + k)*W_ + hE]);
      racc += __shfl_xor(racc,1);
      if (halfE == 0) sR[hE] = racc;
      if (hE < t) {
        float eacc = 0.f;
        #pragma unroll
        for (int k = 0; k < 16; ++k)
          eacc += gload(&exEE[(((long)par*B_ + b)*NB2_ + halfE*16 + k)*W_ + hE]);
        eacc += __shfl_xor(eacc,1);
        if (halfE == 0) sEEc[hE] = -2.f*THETA_*sAt[t-1-hE]*eacc;
      }
    }
    __syncthreads();
    if (tid < 128) {
      float macc = 0.f;
      for (int u = 0; u < t; ++u) macc = fmaf(sEEc[u], sA1[u][tid], macc);
      float z = sZ1[tid], sg = sigf(z);
      sDZ[t][tid] = 2.f*(sR[tid] + macc)*sg*(1.f + z*(1.f - sg));
    }
    __syncthreads();
  }

  // ---- epilogue ----
  if (tid < 128) {
    if (blk == 0) {
      float mm = ETA_*sMB1[tid] - THETA_*sDZ[127][tid];
      mb1[b*W_ + tid] = mm;
      pb1[b*W_ + tid] = PDEC_*sB1[tid] + mm;
    }
  } else if (tid < 160) {
    int j = tid-128;
    float mm = ETA_*sMB2[j] - 2.f*THETA_*sEh[127][j];
    mb2[b*D_ + j0+j] = mm;
    pb2[b*D_ + j0+j] = PDEC_*sB2[j] + mm;
  }
  for (int i = tid; i < 128*4; i += 256) {
    int t2 = i >> 2, hh = (i & 3) + blk*4;
    dz1o[((long)b*SEG_+t2)*W_ + hh] = sDZ[t2][hh];
    a1o [((long)b*SEG_+t2)*W_ + hh] = sA1[t2][hh];
  }
  for (int i = tid; i < 128*32; i += 256) {
    int t2 = i >> 5, jj = i & 31;
    eo[((long)b*SEG_+t2)*D_ + j0+jj] = sEh[t2][jj];
  }
}

// ---------------- weight/momentum reconstruction --------------------------
__global__ __launch_bounds__(256) void k_recon(
  float* __restrict__ pW1, float* __restrict__ mW1,
  float* __restrict__ pW2T, float* __restrict__ mW2T,
  const float* __restrict__ KMp, const float* __restrict__ Eh,
  const float* __restrict__ DZ1, const float* __restrict__ A1h,
  const float* __restrict__ coef)
{
  __shared__ float s1[16][33];
  __shared__ float s2[16][65];
  __shared__ float sCA[128], sCE[128];
  int dt = blockIdx.x, ht = blockIdx.y, kb = blockIdx.z;
  int kind = kb >> 1, b = kb & 1;
  int tid = threadIdx.x;
  int d0 = dt*32, hb = ht*64;
  const float* in1 = (kind ? Eh : KMp) + (long)b*SEG_*D_;
  const float* in2 = (kind ? A1h : DZ1) + (long)b*SEG_*W_;
  float* Pb = (kind ? pW2T : pW1) + (long)b*131072;
  float* Mb = (kind ? mW2T : mW1) + (long)b*131072;
  float f = kind ? -2.f*THETA_ : -THETA_;
  if (tid < 128) {
    sCA[tid] = f*coef[127 - tid];
    sCE[tid] = f*coef[128 + 127 - tid];
  }
  __syncthreads();
  int dd = tid >> 3, le = tid & 7;
  float accP[8] = {}, accM[8] = {};
  for (int u0 = 0; u0 < 128; u0 += 16) {
    for (int i = tid; i < 16*32; i += 256) {
      int uu = i >> 5, d2 = i & 31;
      s1[uu][d2] = in1[(long)(u0+uu)*D_ + d0 + d2];
    }
    for (int i = tid; i < 16*64; i += 256) {
      int uu = i >> 6, hl = i & 63;
      s2[uu][hl] = in2[(long)(u0+uu)*W_ + hb + hl];
    }
    __syncthreads();
    #pragma unroll
    for (int uu = 0; uu < 16; uu++) {
      float a = s1[uu][dd];
      float cAu = sCA[u0+uu], cEu = sCE[u0+uu];
      #pragma unroll
      for (int k = 0; k < 8; k++) {
        float v = a * s2[uu][k*8 + le];
        accP[k] = fmaf(cAu, v, accP[k]);
        accM[k] = fmaf(cEu, v, accM[k]);
      }
    }
    __syncthreads();
  }
  float b128 = coef[256 + 128];
  float eA   = ETA_*coef[127];
  float e128 = ETA_*coef[128 + 127];
  #pragma unroll
  for (int k = 0; k < 8; k++) {
    long idx = (long)(d0+dd)*W_ + hb + k*8 + le;
    float Po = Pb[idx], Mo = Mb[idx];
    Pb[idx] = b128*Po + eA*Mo + accP[k];
    Mb[idx] = e128*Mo + accM[k];
  }
}

// ---------------- host launcher ----------------
static inline void gemm(const float* A, const float* Bm, const float* bias, float* C,
                        int M, int N, int K, long sA, long sB, long sC, long sBias,
                        int batch, int bt, int silu_, hipStream_t st)
{
  dim3 g(N/64, (M+63)/64, batch), blk(256);
  if (!bt && !silu_) k_gemm<0,0><<<g,blk,0,st>>>(A,Bm,bias,C,M,N,K,sA,sB,sC,sBias);
  else if (!bt && silu_) k_gemm<0,1><<<g,blk,0,st>>>(A,Bm,bias,C,M,N,K,sA,sB,sC,sBias);
  else k_gemm<1,0><<<g,blk,0,st>>>(A,Bm,bias,C,M,N,K,sA,sB,sC,sBias);
}

extern "C" void kernel_launch(void* const* d_in, const int* in_sizes, int n_in,
                              void* d_out, int out_size, void* d_ws, size_t ws_size,
                              hipStream_t stream)
{
  (void)in_sizes; (void)n_in; (void)out_size; (void)ws_size;
  const int*   x     = (const int*)  d_in[0];
  const float* emb   = (const float*)d_in[1];
  const float* pers  = (const float*)d_in[2];
  const float* Wq    = (const float*)d_in[3];
  const float* bq    = (const float*)d_in[4];
  const float* Wk    = (const float*)d_in[5];
  const float* bk    = (const float*)d_in[6];
  const float* Wv    = (const float*)d_in[7];
  const float* bv    = (const float*)d_in[8];
  const float* aiw   = (const float*)d_in[9];
  const float* aib   = (const float*)d_in[10];
  const float* aow   = (const float*)d_in[11];
  const float* aob   = (const float*)d_in[12];
  const float* mW1in = (const float*)d_in[13];
  const float* mb1in = (const float*)d_in[14];
  const float* mW2in = (const float*)d_in[15];
  const float* mb2in = (const float*)d_in[16];
  const float* headw = (const float*)d_in[17];
  const float* headb = (const float*)d_in[18];
  float* out = (float*)d_out;
  float* ws  = (float*)d_ws;

  hipMemsetAsync(ws + MOM, 0, MOMSZ*sizeof(float), stream);
  hipMemsetAsync(ws + ZEROB, 0, 128*sizeof(float), stream);
  hipMemsetAsync(ws + CBAR, 0, (size_t)B_*NB2_*FSTR_*sizeof(int), stream);
  k_embed<<<dim3(B_*N_), dim3(256), 0, stream>>>(x, emb, ws+XEMB);
  k_init<<<dim3((2*PER_+255)/256), dim3(256), 0, stream>>>(
      mW1in, mb1in, mW2in, mb2in, ws+PW1, ws+PB1, ws+PW2T, ws+PB2);
  k_coef<<<dim3(1), dim3(64), 0, stream>>>(ws+COEF);

  for (int s = 0; s < NSEG_; s++) {
    const float* segA = ws + XEMB + (size_t)s*SEG_*D_;
    // Q-proj (MFMA), l2n
    k_mf<0,0,0><<<dim3(8,1,B_), dim3(256), 0, stream>>>(
        segA, Wq, bq, ws+Q1, nullptr, SEG_, D_, D_, (long)N_*D_, 0, (long)SEG_*D_, 0, 0);
    k_l2n<<<dim3(B_*SEG_), dim3(256), 0, stream>>>(ws+Q1);
    // retrieve: AH = silu(Q1@W1+b1) [fp32 64², 8 blocks]; HBUF = AH@W2+b2 (MFMA BT)
    gemm(ws+Q1, ws+PW1, ws+PB1, ws+AH, SEG_, W_, D_, (long)SEG_*D_, (long)D_*W_, (long)SEG_*W_, W_, B_, 0, 1, stream);
    k_mf<1,0,0><<<dim3(8,1,B_), dim3(256), 0, stream>>>(
        ws+AH, ws+PW2T, ws+PB2, ws+HBUF, nullptr, SEG_, D_, W_,
        (long)SEG_*W_, (long)D_*W_, (long)SEG_*D_, D_, 0);
    // attention (concat fused into QKV GEMM)
    k_qkv_mfma<<<dim3(3*D_/128, (B_*T_+127)/128), dim3(256), 0, stream>>>(
        pers, ws+HBUF, ws+XEMB, s, aiw, aib, ws+QKV);
    k_attn<<<dim3(8, NH_, B_), dim3(256), 0, stream>>>(ws+QKV, ws+ATTN);
    k_mf<0,0,0><<<dim3(D_/128, 2, 1), dim3(256), 0, stream>>>(
        ws+ATTN, aow, aob, ws+SEGO, nullptr, B_*SEG_, D_, D_, 0, 0, 0, 0, 0);
    // fused K/V/Q projections of seg_out (MFMA), joint l2n
    k_gemmkvq_m<<<dim3(24, 2), dim3(256), 0, stream>>>(
        ws+SEGO, Wk, bk, Wv, bv, Wq, bq, ws+KM, ws+VM, ws+Q1);
    k_l2n2<<<dim3(2*B_*SEG_), dim3(256), 0, stream>>>(ws+KM, ws+Q1, B_*SEG_);
    // scan precompute: {Q1K, Q1Km} fused (fp32); G = K@K^T (fp32 64², 8 blocks)
    k_gemm2<<<dim3(2, 2, B_), dim3(256), 0, stream>>>(
        ws+KM, ws+PW1, ws+MW1, ws+AQ1K, ws+AQ1KM,
        D_, (long)SEG_*D_, (long)D_*W_, (long)SEG_*W_);
    gemm(ws+KM, ws+KM, ws+ZEROB, ws+AGRAM, SEG_, SEG_, D_,
         (long)SEG_*D_, (long)SEG_*D_, (long)SEG_*SEG_, 0, B_, 1, 0, stream);
    // the scan (round-10 structure)
    k_scan<<<dim3(NB2_, B_), dim3(256), 0, stream>>>(
        ws+PW2T, ws+MW2T, ws+PB1, ws+MB1, ws+PB2, ws+MB2, ws+VM,
        ws+AQ1K, ws+AQ1KM, ws+AGRAM,
        ws+ADZ1, ws+AA1H, ws+AEH,
        ws+AEXR, ws+AEXEE,
        ws+COEF, (int*)(ws+CBAR), s);
    // reconstruct weights/momenta
    k_recon<<<dim3(32, 2, 4), dim3(256), 0, stream>>>(
        ws+PW1, ws+MW1, ws+PW2T, ws+MW2T,
        ws+KM, ws+AEH, ws+ADZ1, ws+AA1H, ws+COEF);
    // mem_out = mlp(p_new, Q1); OUTS = SEGO * mem_out (fused MFMA epilogue)
    gemm(ws+Q1, ws+PW1, ws+PB1, ws+AH, SEG_, W_, D_, (long)SEG_*D_, (long)D_*W_, (long)SEG_*W_, W_, B_, 0, 1, stream);
    k_mf<1,0,1><<<dim3(8,1,B_), dim3(256), 0, stream>>>(
        ws+AH, ws+PW2T, ws+PB2, ws+OUTS + (size_t)s*SEG_*D_, ws+SEGO,
        SEG_, D_, W_, (long)SEG_*W_, (long)D_*W_, (long)N_*D_, D_, (long)SEG_*D_);
  }
  // head via bf16-split MFMA
  k_head_mfma<<<dim3(V_/128, (B_*N_)/128), dim3(256), 0, stream>>>(
      ws+OUTS, headw, headb, out, B_*N_, V_, D_);
}

// Round 14
// 7188.882 us; speedup vs baseline: 1.0681x; 1.0399x over previous
//
#include <hip/hip_runtime.h>
#include <math.h>

#define D_    1024
#define B_    2
#define N_    512
#define SEG_  128
#define NSEG_ 4
#define NPT_  16
#define T_    272
#define NH_   16
#define HD_   64
#define W_    128
#define V_    32000

#define THETA_ 0.1f
#define ETA_   0.9f
#define PDEC_  0.99f
#define EPSN_  1e-6f
#define NB2_  32
#define FSTR_ 32

typedef __bf16 bf16x8 __attribute__((ext_vector_type(8)));
typedef float  f32x4  __attribute__((ext_vector_type(4)));

// ---------------- workspace layout (float offsets) ----------------
static const size_t XEMB = 0;
static const size_t OUTS = XEMB + (size_t)B_*N_*D_;
static const size_t PW1  = OUTS + (size_t)B_*N_*D_;
static const size_t PB1  = PW1  + (size_t)B_*D_*W_;
static const size_t PW2T = PB1  + (size_t)B_*W_;
static const size_t PB2  = PW2T + (size_t)B_*D_*W_;
static const size_t MOM  = PB2  + (size_t)B_*D_;
static const size_t MW1  = MOM;
static const size_t MB1  = MW1  + (size_t)B_*D_*W_;
static const size_t MW2T = MB1  + (size_t)B_*W_;
static const size_t MB2  = MW2T + (size_t)B_*D_*W_;
static const size_t MOMSZ = (size_t)B_*(D_*W_ + W_ + D_*W_ + D_);
static const size_t Q1   = MOM  + MOMSZ;
static const size_t AH   = Q1   + (size_t)B_*SEG_*D_;
static const size_t HBUF = AH   + (size_t)B_*SEG_*W_;
static const size_t COMB = HBUF + (size_t)B_*SEG_*D_;
static const size_t QKV  = COMB + (size_t)B_*T_*D_;
static const size_t ATTN = QKV  + (size_t)B_*T_*3*D_;
static const size_t SEGO = ATTN + (size_t)B_*SEG_*D_;
static const size_t KM   = SEGO + (size_t)B_*SEG_*D_;
static const size_t VM   = KM   + (size_t)B_*SEG_*D_;
static const size_t MEMO = VM   + (size_t)B_*SEG_*D_;
static const size_t WSEND = MEMO + (size_t)B_*SEG_*D_;

// scan-phase buffers ALIAS the QKV region
static const size_t AQ1K  = QKV;
static const size_t AQ1KM = AQ1K  + 32768;
static const size_t AGRAM = AQ1KM + 32768;
static const size_t ADZ1  = AGRAM + 32768;
static const size_t AA1H  = ADZ1  + 32768;
static const size_t AEH   = AA1H  + 32768;
static const size_t AEXR  = AEH + (size_t)B_*SEG_*D_;
static const size_t AEXEE = AEXR + 16384;
// persistent tail
static const size_t COEF  = WSEND;
static const size_t ZEROB = COEF + 512;
static const size_t CBAR  = ZEROB + 128;

__device__ __forceinline__ float sigf(float x) { return 1.f/(1.f+expf(-x)); }

__device__ __forceinline__ void gstore(float* p, float v) {
  __hip_atomic_store(p, v, __ATOMIC_RELAXED, __HIP_MEMORY_SCOPE_AGENT);
}
__device__ __forceinline__ float gload(const float* p) {
  return __hip_atomic_load(p, __ATOMIC_RELAXED, __HIP_MEMORY_SCOPE_AGENT);
}

// RNE bf16 split: a ≈ float(h) + float(l)
__device__ __forceinline__ void bsplit(float a, short& h, short& l) {
  unsigned u = __builtin_bit_cast(unsigned, a);
  unsigned hb = (u + 0x7fffu + ((u >> 16) & 1u)) >> 16;
  h = (short)hb;
  float hf = __builtin_bit_cast(float, hb << 16);
  float r = a - hf;
  unsigned ur = __builtin_bit_cast(unsigned, r);
  unsigned lb = (ur + 0x7fffu + ((ur >> 16) & 1u)) >> 16;
  l = (short)lb;
}

// ---------------- fp32 64x64 GEMM (tiny-grid ops: AH, Gram) ----------------
template<int BT, int SILU>
__global__ __launch_bounds__(256) void k_gemm(
    const float* __restrict__ A, const float* __restrict__ Bm,
    const float* __restrict__ bias, float* __restrict__ C,
    int M, int N, int K, long sA, long sB, long sC, long sBias)
{
  __shared__ float As[16][68];
  __shared__ float Bs[16][68];
  int bz = blockIdx.z;
  A += bz*sA; Bm += bz*sB; C += bz*sC; bias += bz*sBias;
  int n0 = blockIdx.x*64, m0 = blockIdx.y*64;
  int tid = threadIdx.x;
  int tx = tid & 15, ty = tid >> 4;
  int r  = tid >> 2;
  int kq = (tid & 3) * 4;
  float acc[4][4] = {};
  for (int k0 = 0; k0 < K; k0 += 16) {
    {
      int row = m0 + r;
      float4 v = make_float4(0.f,0.f,0.f,0.f);
      if (row < M) v = *(const float4*)(A + (long)row*K + k0 + kq);
      As[kq+0][r]=v.x; As[kq+1][r]=v.y; As[kq+2][r]=v.z; As[kq+3][r]=v.w;
    }
    if (BT) {
      int row = n0 + r;
      float4 v = *(const float4*)(Bm + (long)row*K + k0 + kq);
      Bs[kq+0][r]=v.x; Bs[kq+1][r]=v.y; Bs[kq+2][r]=v.z; Bs[kq+3][r]=v.w;
    } else {
      int c = tid & 63, r4 = tid >> 6;
      #pragma unroll
      for (int p = 0; p < 4; p++) {
        int kk = r4 + p*4;
        Bs[kk][c] = Bm[(long)(k0+kk)*N + n0 + c];
      }
    }
    __syncthreads();
    #pragma unroll
    for (int kk = 0; kk < 16; kk++) {
      float av[4], bv[4];
      #pragma unroll
      for (int i=0;i<4;i++) av[i] = As[kk][ty*4+i];
      #pragma unroll
      for (int j=0;j<4;j++) bv[j] = Bs[kk][tx*4+j];
      #pragma unroll
      for (int i=0;i<4;i++)
        #pragma unroll
        for (int j=0;j<4;j++)
          acc[i][j] = fmaf(av[i], bv[j], acc[i][j]);
    }
    __syncthreads();
  }
  #pragma unroll
  for (int i=0;i<4;i++) {
    int row = m0 + ty*4 + i;
    if (row >= M) continue;
    #pragma unroll
    for (int j=0;j<4;j++) {
      int col = n0 + tx*4 + j;
      float v = acc[i][j] + bias[col];
      if (SILU) v = v * sigf(v);
      C[(long)row*N + col] = v;
    }
  }
}

// ------- universal bf16-split MFMA GEMM; MT = row-tile (128 or 64) -------
template<int BT, int SILU, int MUL, int MT>
__global__ __launch_bounds__(256) void k_mf(
    const float* __restrict__ A, const float* __restrict__ Bm,
    const float* __restrict__ bias, float* __restrict__ C,
    const float* __restrict__ aux,
    int M, int N, int K, long sA, long sB, long sC, long sBias, long sAux)
{
  __shared__ short Ah[MT][48];
  __shared__ short Al[MT][48];
  __shared__ short Bh[32][132];
  __shared__ short Bl[32][132];
  int bz = blockIdx.z;
  A += bz*sA; Bm += bz*sB; C += bz*sC; bias += bz*sBias;
  if (MUL) aux += bz*sAux;
  int n0 = blockIdx.x*128, m0 = blockIdx.y*MT;
  int tid = threadIdx.x;
  int wave = tid >> 6, lane = tid & 63;
  constexpr int NF = (MT == 128) ? 4 : 2;
  int wm = (MT == 128) ? (wave >> 1) * 64 : 0;
  int wn = (MT == 128) ? (wave & 1) * 64 : wave * 32;
  int lrow = lane & 15, lk = (lane >> 4) * 8;
  int arow0 = (MT == 128) ? min(m0 + (tid >> 1), M-1) : min(m0 + (tid >> 2), M-1);
  f32x4 acc[4][NF] = {};
  for (int k0 = 0; k0 < K; k0 += 32) {
    __syncthreads();
    if (MT == 128) { // 16 elems/thread
      int r = tid >> 1, kq = (tid & 1) * 16;
      const float* ap = A + (long)arow0*K + k0 + kq;
      #pragma unroll
      for (int q = 0; q < 16; q += 4) {
        float4 v = *(const float4*)(ap + q);
        short h0,l0,h1,l1,h2,l2,h3,l3;
        bsplit(v.x,h0,l0); bsplit(v.y,h1,l1); bsplit(v.z,h2,l2); bsplit(v.w,h3,l3);
        *(short4*)&Ah[r][kq+q] = make_short4(h0,h1,h2,h3);
        *(short4*)&Al[r][kq+q] = make_short4(l0,l1,l2,l3);
      }
    } else {         // MT==64: 8 elems/thread
      int r = tid >> 2, kq = (tid & 3) * 8;
      const float* ap = A + (long)arow0*K + k0 + kq;
      #pragma unroll
      for (int q = 0; q < 8; q += 4) {
        float4 v = *(const float4*)(ap + q);
        short h0,l0,h1,l1,h2,l2,h3,l3;
        bsplit(v.x,h0,l0); bsplit(v.y,h1,l1); bsplit(v.z,h2,l2); bsplit(v.w,h3,l3);
        *(short4*)&Ah[r][kq+q] = make_short4(h0,h1,h2,h3);
        *(short4*)&Al[r][kq+q] = make_short4(l0,l1,l2,l3);
      }
    }
    if (BT) {
      int nn = tid >> 1, kq2 = (tid & 1) * 16;
      const float* bp = Bm + (long)(n0+nn)*K + k0 + kq2;
      #pragma unroll
      for (int q = 0; q < 16; q += 4) {
        float4 v = *(const float4*)(bp + q);
        short h0,l0,h1,l1,h2,l2,h3,l3;
        bsplit(v.x,h0,l0); bsplit(v.y,h1,l1); bsplit(v.z,h2,l2); bsplit(v.w,h3,l3);
        Bh[kq2+q+0][nn]=h0; Bh[kq2+q+1][nn]=h1; Bh[kq2+q+2][nn]=h2; Bh[kq2+q+3][nn]=h3;
        Bl[kq2+q+0][nn]=l0; Bl[kq2+q+1][nn]=l1; Bl[kq2+q+2][nn]=l2; Bl[kq2+q+3][nn]=l3;
      }
    } else {
      int kr = tid >> 3, nq = (tid & 7) * 16;
      const float* bp = Bm + (long)(k0 + kr)*N + n0 + nq;
      #pragma unroll
      for (int q = 0; q < 16; q += 4) {
        float4 v = *(const float4*)(bp + q);
        short h0,l0,h1,l1,h2,l2,h3,l3;
        bsplit(v.x,h0,l0); bsplit(v.y,h1,l1); bsplit(v.z,h2,l2); bsplit(v.w,h3,l3);
        *(short4*)&Bh[kr][nq+q] = make_short4(h0,h1,h2,h3);
        *(short4*)&Bl[kr][nq+q] = make_short4(l0,l1,l2,l3);
      }
    }
    __syncthreads();
    bf16x8 bh[NF], bl[NF];
    #pragma unroll
    for (int nf = 0; nf < NF; nf++) {
      int col = wn + nf*16 + lrow;
      #pragma unroll
      for (int j = 0; j < 8; j++) {
        bh[nf][j] = __builtin_bit_cast(__bf16, Bh[lk+j][col]);
        bl[nf][j] = __builtin_bit_cast(__bf16, Bl[lk+j][col]);
      }
    }
    #pragma unroll
    for (int mf = 0; mf < 4; mf++) {
      int ar2 = wm + mf*16 + lrow;
      bf16x8 ah = *(const bf16x8*)&Ah[ar2][lk];
      bf16x8 al = *(const bf16x8*)&Al[ar2][lk];
      #pragma unroll
      for (int nf = 0; nf < NF; nf++) {
        acc[mf][nf] = __builtin_amdgcn_mfma_f32_16x16x32_bf16(ah, bh[nf], acc[mf][nf], 0, 0, 0);
        acc[mf][nf] = __builtin_amdgcn_mfma_f32_16x16x32_bf16(ah, bl[nf], acc[mf][nf], 0, 0, 0);
        acc[mf][nf] = __builtin_amdgcn_mfma_f32_16x16x32_bf16(al, bh[nf], acc[mf][nf], 0, 0, 0);
      }
    }
  }
  #pragma unroll
  for (int mf = 0; mf < 4; mf++) {
    #pragma unroll
    for (int nf = 0; nf < NF; nf++) {
      int col = n0 + wn + nf*16 + lrow;
      float bv = bias[col];
      #pragma unroll
      for (int j = 0; j < 4; j++) {
        int row = m0 + wm + mf*16 + (lane >> 4)*4 + j;
        if (row < M) {
          float v = acc[mf][nf][j] + bv;
          if (SILU) v = v * sigf(v);
          if (MUL)  v *= aux[(long)row*N + col];
          C[(long)row*N + col] = v;
        }
      }
    }
  }
}

// ------- dual-output 64x64 fp32 GEMM ----
__global__ __launch_bounds__(256) void k_gemm2(
    const float* __restrict__ A, const float* __restrict__ B1,
    const float* __restrict__ B2, float* __restrict__ C1, float* __restrict__ C2,
    int K, long sA, long sB, long sC)
{
  __shared__ float As[16][68];
  __shared__ float B1s[16][68];
  __shared__ float B2s[16][68];
  int bz = blockIdx.z;
  A += bz*sA; B1 += bz*sB; B2 += bz*sB; C1 += bz*sC; C2 += bz*sC;
  int n0 = blockIdx.x*64, m0 = blockIdx.y*64;
  int tid = threadIdx.x;
  int tx = tid & 15, ty = tid >> 4;
  int r  = tid >> 2;
  int kq = (tid & 3) * 4;
  float acc1[4][4] = {}, acc2[4][4] = {};
  for (int k0 = 0; k0 < K; k0 += 16) {
    {
      float4 v = *(const float4*)(A + (long)(m0+r)*K + k0 + kq);
      As[kq+0][r]=v.x; As[kq+1][r]=v.y; As[kq+2][r]=v.z; As[kq+3][r]=v.w;
    }
    {
      int c = tid & 63, r4 = tid >> 6;
      #pragma unroll
      for (int p = 0; p < 4; p++) {
        int kk = r4 + p*4;
        B1s[kk][c] = B1[(long)(k0+kk)*W_ + n0 + c];
        B2s[kk][c] = B2[(long)(k0+kk)*W_ + n0 + c];
      }
    }
    __syncthreads();
    #pragma unroll
    for (int kk = 0; kk < 16; kk++) {
      float av[4], b1v[4], b2v[4];
      #pragma unroll
      for (int i=0;i<4;i++) av[i] = As[kk][ty*4+i];
      #pragma unroll
      for (int j=0;j<4;j++) { b1v[j] = B1s[kk][tx*4+j]; b2v[j] = B2s[kk][tx*4+j]; }
      #pragma unroll
      for (int i=0;i<4;i++)
        #pragma unroll
        for (int j=0;j<4;j++) {
          acc1[i][j] = fmaf(av[i], b1v[j], acc1[i][j]);
          acc2[i][j] = fmaf(av[i], b2v[j], acc2[i][j]);
        }
    }
    __syncthreads();
  }
  #pragma unroll
  for (int i=0;i<4;i++) {
    int row = m0 + ty*4 + i;
    #pragma unroll
    for (int j=0;j<4;j++) {
      int col = n0 + tx*4 + j;
      C1[(long)row*W_ + col] = acc1[i][j];
      C2[(long)row*W_ + col] = acc2[i][j];
    }
  }
}

// ------- QKV MFMA GEMM with fused concat (MT=128) -------
__global__ __launch_bounds__(256) void k_qkv_mfma(
    const float* __restrict__ pers, const float* __restrict__ hbuf,
    const float* __restrict__ xemb, int s,
    const float* __restrict__ Bm, const float* __restrict__ bias,
    float* __restrict__ C)
{
  __shared__ short Ah[128][48];
  __shared__ short Al[128][48];
  __shared__ short Bh[32][132];
  __shared__ short Bl[32][132];
  const int M = B_*T_, N = 3*D_, K = D_;
  int n0 = blockIdx.x*128, m0 = blockIdx.y*128;
  int tid = threadIdx.x;
  int wave = tid >> 6, lane = tid & 63;
  int wm = (wave >> 1) * 64, wn = (wave & 1) * 64;
  int lrow = lane & 15, lk = (lane >> 4) * 8;
  int grow = min(m0 + (tid >> 1), M-1);
  int b = grow >= T_ ? 1 : 0;
  int rt = grow - b*T_;
  const float* asrc;
  if (rt < NPT_)            asrc = pers + (long)rt*D_;
  else if (rt < NPT_+SEG_)  asrc = hbuf + ((long)b*SEG_ + (rt-NPT_))*D_;
  else                      asrc = xemb + ((long)b*N_ + s*SEG_ + (rt-NPT_-SEG_))*D_;
  f32x4 acc[4][4] = {};
  for (int k0 = 0; k0 < K; k0 += 32) {
    __syncthreads();
    {
      int r = tid >> 1, kq = (tid & 1) * 16;
      const float* ap = asrc + k0 + kq;
      #pragma unroll
      for (int q = 0; q < 16; q += 4) {
        float4 v = *(const float4*)(ap + q);
        short h0,l0,h1,l1,h2,l2,h3,l3;
        bsplit(v.x,h0,l0); bsplit(v.y,h1,l1); bsplit(v.z,h2,l2); bsplit(v.w,h3,l3);
        *(short4*)&Ah[r][kq+q] = make_short4(h0,h1,h2,h3);
        *(short4*)&Al[r][kq+q] = make_short4(l0,l1,l2,l3);
      }
    }
    {
      int kr = tid >> 3, nq = (tid & 7) * 16;
      const float* bp = Bm + (long)(k0 + kr)*N + n0 + nq;
      #pragma unroll
      for (int q = 0; q < 16; q += 4) {
        float4 v = *(const float4*)(bp + q);
        short h0,l0,h1,l1,h2,l2,h3,l3;
        bsplit(v.x,h0,l0); bsplit(v.y,h1,l1); bsplit(v.z,h2,l2); bsplit(v.w,h3,l3);
        *(short4*)&Bh[kr][nq+q] = make_short4(h0,h1,h2,h3);
        *(short4*)&Bl[kr][nq+q] = make_short4(l0,l1,l2,l3);
      }
    }
    __syncthreads();
    bf16x8 bh[4], bl[4];
    #pragma unroll
    for (int nf = 0; nf < 4; nf++) {
      int col = wn + nf*16 + lrow;
      #pragma unroll
      for (int j = 0; j < 8; j++) {
        bh[nf][j] = __builtin_bit_cast(__bf16, Bh[lk+j][col]);
        bl[nf][j] = __builtin_bit_cast(__bf16, Bl[lk+j][col]);
      }
    }
    #pragma unroll
    for (int mf = 0; mf < 4; mf++) {
      int ar2 = wm + mf*16 + lrow;
      bf16x8 ah = *(const bf16x8*)&Ah[ar2][lk];
      bf16x8 al = *(const bf16x8*)&Al[ar2][lk];
      #pragma unroll
      for (int nf = 0; nf < 4; nf++) {
        acc[mf][nf] = __builtin_amdgcn_mfma_f32_16x16x32_bf16(ah, bh[nf], acc[mf][nf], 0, 0, 0);
        acc[mf][nf] = __builtin_amdgcn_mfma_f32_16x16x32_bf16(ah, bl[nf], acc[mf][nf], 0, 0, 0);
        acc[mf][nf] = __builtin_amdgcn_mfma_f32_16x16x32_bf16(al, bh[nf], acc[mf][nf], 0, 0, 0);
      }
    }
  }
  #pragma unroll
  for (int mf = 0; mf < 4; mf++) {
    #pragma unroll
    for (int nf = 0; nf < 4; nf++) {
      int col = n0 + wn + nf*16 + lrow;
      float bv = bias[col];
      #pragma unroll
      for (int j = 0; j < 4; j++) {
        int row = m0 + wm + mf*16 + (lane >> 4)*4 + j;
        if (row < M) C[(long)row*N + col] = acc[mf][nf][j] + bv;
      }
    }
  }
}

// ------- fused K/V/Q projection via bf16-split MFMA (MT=64 tiles) ----
__global__ __launch_bounds__(256) void k_gemmkvq_m(
    const float* __restrict__ A,
    const float* __restrict__ Wk, const float* __restrict__ bk,
    const float* __restrict__ Wv, const float* __restrict__ bv,
    const float* __restrict__ Wq, const float* __restrict__ bq,
    float* __restrict__ KMo, float* __restrict__ VMo, float* __restrict__ Q1o)
{
  __shared__ short Ah[64][48];
  __shared__ short Al[64][48];
  __shared__ short Bh[32][132];
  __shared__ short Bl[32][132];
  int bx = blockIdx.x;
  int sel = bx >> 3;
  int n0 = (bx & 7) * 128;
  int m0 = blockIdx.y * 64;
  const float* Bm   = sel == 0 ? Wk : sel == 1 ? Wv : Wq;
  const float* bias = sel == 0 ? bk : sel == 1 ? bv : bq;
  float* C          = sel == 0 ? KMo : sel == 1 ? VMo : Q1o;
  int tid = threadIdx.x;
  int wave = tid >> 6, lane = tid & 63;
  int wn = wave * 32;
  int lrow = lane & 15, lk = (lane >> 4) * 8;
  f32x4 acc[4][2] = {};
  for (int k0 = 0; k0 < D_; k0 += 32) {
    __syncthreads();
    {
      int r = tid >> 2, kq = (tid & 3) * 8;
      const float* ap = A + (long)(m0 + r)*D_ + k0 + kq;
      #pragma unroll
      for (int q = 0; q < 8; q += 4) {
        float4 v = *(const float4*)(ap + q);
        short h0,l0,h1,l1,h2,l2,h3,l3;
        bsplit(v.x,h0,l0); bsplit(v.y,h1,l1); bsplit(v.z,h2,l2); bsplit(v.w,h3,l3);
        *(short4*)&Ah[r][kq+q] = make_short4(h0,h1,h2,h3);
        *(short4*)&Al[r][kq+q] = make_short4(l0,l1,l2,l3);
      }
    }
    {
      int kr = tid >> 3, nq = (tid & 7) * 16;
      const float* bp = Bm + (long)(k0 + kr)*D_ + n0 + nq;
      #pragma unroll
      for (int q = 0; q < 16; q += 4) {
        float4 v = *(const float4*)(bp + q);
        short h0,l0,h1,l1,h2,l2,h3,l3;
        bsplit(v.x,h0,l0); bsplit(v.y,h1,l1); bsplit(v.z,h2,l2); bsplit(v.w,h3,l3);
        *(short4*)&Bh[kr][nq+q] = make_short4(h0,h1,h2,h3);
        *(short4*)&Bl[kr][nq+q] = make_short4(l0,l1,l2,l3);
      }
    }
    __syncthreads();
    bf16x8 bh[2], bl[2];
    #pragma unroll
    for (int nf = 0; nf < 2; nf++) {
      int col = wn + nf*16 + lrow;
      #pragma unroll
      for (int j = 0; j < 8; j++) {
        bh[nf][j] = __builtin_bit_cast(__bf16, Bh[lk+j][col]);
        bl[nf][j] = __builtin_bit_cast(__bf16, Bl[lk+j][col]);
      }
    }
    #pragma unroll
    for (int mf = 0; mf < 4; mf++) {
      int ar2 = mf*16 + lrow;
      bf16x8 ah = *(const bf16x8*)&Ah[ar2][lk];
      bf16x8 al = *(const bf16x8*)&Al[ar2][lk];
      #pragma unroll
      for (int nf = 0; nf < 2; nf++) {
        acc[mf][nf] = __builtin_amdgcn_mfma_f32_16x16x32_bf16(ah, bh[nf], acc[mf][nf], 0, 0, 0);
        acc[mf][nf] = __builtin_amdgcn_mfma_f32_16x16x32_bf16(ah, bl[nf], acc[mf][nf], 0, 0, 0);
        acc[mf][nf] = __builtin_amdgcn_mfma_f32_16x16x32_bf16(al, bh[nf], acc[mf][nf], 0, 0, 0);
      }
    }
  }
  #pragma unroll
  for (int mf = 0; mf < 4; mf++) {
    #pragma unroll
    for (int nf = 0; nf < 2; nf++) {
      int col = n0 + wn + nf*16 + lrow;
      float bvx = bias[col];
      #pragma unroll
      for (int j = 0; j < 4; j++) {
        int row = m0 + mf*16 + (lane >> 4)*4 + j;
        C[(long)row*D_ + col] = acc[mf][nf][j] + bvx;
      }
    }
  }
}

// ------- head GEMM via bf16-split MFMA (MT=128) -------
__global__ __launch_bounds__(256) void k_head_mfma(
    const float* __restrict__ A, const float* __restrict__ Bm,
    const float* __restrict__ bias, float* __restrict__ C,
    int M, int N, int K)
{
  __shared__ short Ah[128][48];
  __shared__ short Al[128][48];
  __shared__ short Bh[32][132];
  __shared__ short Bl[32][132];
  int n0 = blockIdx.x*128, m0 = blockIdx.y*128;
  int tid = threadIdx.x;
  int wave = tid >> 6, lane = tid & 63;
  int wm = (wave >> 1) * 64, wn = (wave & 1) * 64;
  int lrow = lane & 15, lk = (lane >> 4) * 8;
  f32x4 acc[4][4] = {};
  for (int k0 = 0; k0 < K; k0 += 32) {
    __syncthreads();
    {
      int r = tid >> 1, kq = (tid & 1) * 16;
      const float* ap = A + (long)(m0 + r)*K + k0 + kq;
      #pragma unroll
      for (int q = 0; q < 16; q += 4) {
        float4 v = *(const float4*)(ap + q);
        short h0,l0,h1,l1,h2,l2,h3,l3;
        bsplit(v.x,h0,l0); bsplit(v.y,h1,l1); bsplit(v.z,h2,l2); bsplit(v.w,h3,l3);
        *(short4*)&Ah[r][kq+q] = make_short4(h0,h1,h2,h3);
        *(short4*)&Al[r][kq+q] = make_short4(l0,l1,l2,l3);
      }
    }
    {
      int kr = tid >> 3, nq = (tid & 7) * 16;
      const float* bp = Bm + (long)(k0 + kr)*N + n0 + nq;
      #pragma unroll
      for (int q = 0; q < 16; q += 4) {
        float4 v = *(const float4*)(bp + q);
        short h0,l0,h1,l1,h2,l2,h3,l3;
        bsplit(v.x,h0,l0); bsplit(v.y,h1,l1); bsplit(v.z,h2,l2); bsplit(v.w,h3,l3);
        *(short4*)&Bh[kr][nq+q] = make_short4(h0,h1,h2,h3);
        *(short4*)&Bl[kr][nq+q] = make_short4(l0,l1,l2,l3);
      }
    }
    __syncthreads();
    bf16x8 bh[4], bl[4];
    #pragma unroll
    for (int nf = 0; nf < 4; nf++) {
      int col = wn + nf*16 + lrow;
      #pragma unroll
      for (int j = 0; j < 8; j++) {
        bh[nf][j] = __builtin_bit_cast(__bf16, Bh[lk+j][col]);
        bl[nf][j] = __builtin_bit_cast(__bf16, Bl[lk+j][col]);
      }
    }
    #pragma unroll
    for (int mf = 0; mf < 4; mf++) {
      int arow2 = wm + mf*16 + lrow;
      bf16x8 ah = *(const bf16x8*)&Ah[arow2][lk];
      bf16x8 al = *(const bf16x8*)&Al[arow2][lk];
      #pragma unroll
      for (int nf = 0; nf < 4; nf++) {
        acc[mf][nf] = __builtin_amdgcn_mfma_f32_16x16x32_bf16(ah, bh[nf], acc[mf][nf], 0, 0, 0);
        acc[mf][nf] = __builtin_amdgcn_mfma_f32_16x16x32_bf16(ah, bl[nf], acc[mf][nf], 0, 0, 0);
        acc[mf][nf] = __builtin_amdgcn_mfma_f32_16x16x32_bf16(al, bh[nf], acc[mf][nf], 0, 0, 0);
      }
    }
  }
  #pragma unroll
  for (int mf = 0; mf < 4; mf++) {
    #pragma unroll
    for (int nf = 0; nf < 4; nf++) {
      int col = n0 + wn + nf*16 + lrow;
      float bv = bias[col];
      #pragma unroll
      for (int j = 0; j < 4; j++) {
        int row = m0 + wm + mf*16 + (lane >> 4)*4 + j;
        C[(long)row*N + col] = acc[mf][nf][j] + bv;
      }
    }
  }
}

// ---------------- small kernels ----------------
__global__ void k_embed(const int* __restrict__ x, const float* __restrict__ emb,
                        float* __restrict__ xe)
{
  int row = blockIdx.x, tid = threadIdx.x;
  int idx = x[row];
  float4 v = *(const float4*)(emb + (long)idx*D_ + tid*4);
  *(float4*)(xe + (long)row*D_ + tid*4) = v;
}

#define PER_ 263296L
__global__ void k_init(const float* __restrict__ mW1in, const float* __restrict__ mb1in,
                       const float* __restrict__ mW2in, const float* __restrict__ mb2in,
                       float* __restrict__ pW1, float* __restrict__ pb1,
                       float* __restrict__ pW2T, float* __restrict__ pb2)
{
  long g = (long)blockIdx.x*256 + threadIdx.x;
  if (g >= 2*PER_) return;
  int b = (int)(g / PER_);
  long rr = g % PER_;
  if (rr < 131072)       pW1[(long)b*131072 + rr] = mW1in[rr];
  else if (rr < 131200)  pb1[b*W_ + (rr-131072)] = mb1in[rr-131072];
  else if (rr < 262272) { long l = rr-131200; int j=(int)(l>>7), h=(int)(l&127);
                          pW2T[(long)b*131072 + l] = mW2in[(long)h*D_ + j]; }
  else                   pb2[b*D_ + (rr-262272)] = mb2in[rr-262272];
}

__global__ void k_coef(float* __restrict__ c)
{
  if (blockIdx.x == 0 && threadIdx.x == 0) {
    c[0] = 1.f; c[128] = 1.f;
    float A = 1.f, eta_d = 1.f;
    for (int d = 1; d < 128; d++) {
      eta_d *= ETA_;
      A = PDEC_*A + eta_d;
      c[d] = A;
      c[128 + d] = eta_d;
    }
    c[256] = 1.f;
    float bp = 1.f;
    for (int t = 1; t <= 128; t++) { bp *= PDEC_; c[256 + t] = bp; }
  }
}

__global__ __launch_bounds__(256) void k_l2n(float* __restrict__ X)
{
  long row = blockIdx.x;
  float* p = X + row*D_;
  int tid = threadIdx.x;
  float4 v = *(float4*)(p + tid*4);
  float ss = v.x*v.x + v.y*v.y + v.z*v.z + v.w*v.w;
  for (int o=32;o;o>>=1) ss += __shfl_xor(ss,o);
  __shared__ float wsum[4];
  if ((tid&63)==0) wsum[tid>>6] = ss;
  __syncthreads();
  float tot = wsum[0]+wsum[1]+wsum[2]+wsum[3];
  float sc = 1.f/(sqrtf(tot)+EPSN_);
  v.x*=sc; v.y*=sc; v.z*=sc; v.w*=sc;
  *(float4*)(p + tid*4) = v;
}

// dual-array l2n
__global__ __launch_bounds__(256) void k_l2n2(float* __restrict__ X1, float* __restrict__ X2, int R)
{
  int row = blockIdx.x;
  float* p = (row < R ? X1 + (long)row*D_ : X2 + (long)(row-R)*D_);
  int tid = threadIdx.x;
  float4 v = *(float4*)(p + tid*4);
  float ss = v.x*v.x + v.y*v.y + v.z*v.z + v.w*v.w;
  for (int o=32;o;o>>=1) ss += __shfl_xor(ss,o);
  __shared__ float wsum[4];
  if ((tid&63)==0) wsum[tid>>6] = ss;
  __syncthreads();
  float tot = wsum[0]+wsum[1]+wsum[2]+wsum[3];
  float sc = 1.f/(sqrtf(tot)+EPSN_);
  v.x*=sc; v.y*=sc; v.z*=sc; v.w*=sc;
  *(float4*)(p + tid*4) = v;
}

__global__ __launch_bounds__(256) void k_attn(const float* __restrict__ qkv,
                                              float* __restrict__ outp)
{
  __shared__ float sQ[16][68];
  __shared__ float sKV[64][68];
  __shared__ float sS[16][273];
  int qt = blockIdx.x, head = blockIdx.y, b = blockIdx.z;
  int tid = threadIdx.x;
  const float* base = qkv + (long)b*T_*3*D_;
  int qoff = head*HD_, koff = D_ + head*HD_, voff = 2*D_ + head*HD_;
  int qrow0 = NPT_ + SEG_ + qt*16;
  {
    int rr = tid>>4, c4 = (tid&15)*4;
    float4 v = *(const float4*)(base + (long)(qrow0+rr)*3*D_ + qoff + c4);
    sQ[rr][c4]=v.x; sQ[rr][c4+1]=v.y; sQ[rr][c4+2]=v.z; sQ[rr][c4+3]=v.w;
  }
  __syncthreads();
  for (int j0 = 0; j0 < T_; j0 += 64) {
    int chunk = min(64, T_ - j0);
    {
      int jj = tid>>2, cq = (tid&3)*16;
      if (jj < chunk) {
        #pragma unroll
        for (int q4=0;q4<4;q4++) {
          float4 v = *(const float4*)(base + (long)(j0+jj)*3*D_ + koff + cq + q4*4);
          sKV[jj][cq+q4*4]=v.x; sKV[jj][cq+q4*4+1]=v.y; sKV[jj][cq+q4*4+2]=v.z; sKV[jj][cq+q4*4+3]=v.w;
        }
      }
    }
    __syncthreads();
    int rr = tid>>4, jj0 = tid&15;
    #pragma unroll
    for (int p=0;p<4;p++) {
      int jj = jj0 + p*16;
      if (jj < chunk) {
        float s = 0.f;
        #pragma unroll 8
        for (int c=0;c<HD_;c++) s = fmaf(sQ[rr][c], sKV[jj][c], s);
        s *= 0.125f;
        int jg = j0 + jj, qg = qrow0 + rr;
        if (jg > qg) s = -3.0e38f;
        sS[rr][jg] = s;
      }
    }
    __syncthreads();
  }
  {
    int rr = tid>>4, l16 = tid&15;
    float m = -3.4e38f;
    for (int j=l16; j<T_; j+=16) m = fmaxf(m, sS[rr][j]);
    for (int o=8;o;o>>=1) m = fmaxf(m, __shfl_xor(m,o));
    float sum = 0.f;
    for (int j=l16; j<T_; j+=16) { float e = expf(sS[rr][j]-m); sS[rr][j] = e; sum += e; }
    for (int o=8;o;o>>=1) sum += __shfl_xor(sum,o);
    float inv = 1.f/sum;
    for (int j=l16; j<T_; j+=16) sS[rr][j] *= inv;
  }
  __syncthreads();
  float acc[4] = {0.f,0.f,0.f,0.f};
  int rr = tid>>4, c4 = (tid&15)*4;
  for (int j0 = 0; j0 < T_; j0 += 64) {
    int chunk = min(64, T_ - j0);
    {
      int jj = tid>>2, cq = (tid&3)*16;
      if (jj < chunk) {
        #pragma unroll
        for (int q4=0;q4<4;q4++) {
          float4 v = *(const float4*)(base + (long)(j0+jj)*3*D_ + voff + cq + q4*4);
          sKV[jj][cq+q4*4]=v.x; sKV[jj][cq+q4*4+1]=v.y; sKV[jj][cq+q4*4+2]=v.z; sKV[jj][cq+q4*4+3]=v.w;
        }
      }
    }
    __syncthreads();
    for (int jj=0; jj<chunk; jj++) {
      float p = sS[rr][j0+jj];
      #pragma unroll
      for (int i=0;i<4;i++) acc[i] = fmaf(p, sKV[jj][c4+i], acc[i]);
    }
    __syncthreads();
  }
  float4 o4 = make_float4(acc[0],acc[1],acc[2],acc[3]);
  *(float4*)(outp + ((long)(b*SEG_) + qt*16 + rr)*D_ + head*HD_ + c4) = o4;
}

// ------- fence-free flag barrier ---------
__device__ __forceinline__ void gbar(int* flags, int blk, int gen)
{
  asm volatile("s_waitcnt vmcnt(0) lgkmcnt(0)" ::: "memory");
  __syncthreads();
  if (threadIdx.x == 0)
    __hip_atomic_store(flags + blk*FSTR_, gen, __ATOMIC_RELAXED, __HIP_MEMORY_SCOPE_AGENT);
  if (threadIdx.x < NB2_) {
    while (__hip_atomic_load(flags + threadIdx.x*FSTR_, __ATOMIC_RELAXED,
                             __HIP_MEMORY_SCOPE_AGENT) < gen)
      __builtin_amdgcn_s_sleep(1);
  }
  __syncthreads();
}

// ---- persistent token-space scan (round-10 version) ----
__global__ __launch_bounds__(256) void k_scan(
  const float* __restrict__ pW2T, const float* __restrict__ mW2T,
  float* __restrict__ pb1, float* __restrict__ mb1,
  float* __restrict__ pb2, float* __restrict__ mb2,
  const float* __restrict__ Vm,
  const float* __restrict__ q1k, const float* __restrict__ q1km,
  const float* __restrict__ G,
  float* __restrict__ dz1o, float* __restrict__ a1o, float* __restrict__ eo,
  float* __restrict__ exR, float* __restrict__ exEE,
  const float* __restrict__ coef, int* __restrict__ barbase, int seg)
{
  __shared__ float sDZ[128][129];
  __shared__ float sA1[128][129];
  __shared__ float sEh[128][33];
  __shared__ float sB1[128], sMB1[128], sZ1[128], sR[128];
  __shared__ float sB2[32], sMB2[32];
  __shared__ float sAt[128];
  __shared__ float sBp[129];
  __shared__ float sGc[128];
  __shared__ float sS[128];
  __shared__ float sEEc[128];

  int b = blockIdx.y, blk = blockIdx.x, tid = threadIdx.x;
  int j0 = blk*32;
  int* flags = barbase + b*(NB2_*FSTR_);
  int gbase = seg*200;
  const float* W0 = pW2T + (long)b*131072;
  const float* Wm = mW2T + (long)b*131072;

  int jD = tid >> 3, lD = tid & 7;
  float rD0[16], rDm[16];
  #pragma unroll
  for (int k = 0; k < 16; k++) {
    rD0[k] = W0[(long)(j0+jD)*128 + lD + 8*k];
    rDm[k] = Wm[(long)(j0+jD)*128 + lD + 8*k];
  }
  int hE = tid >> 1, halfE = tid & 1;
  float rE0[16], rEm[16];
  #pragma unroll
  for (int q = 0; q < 16; q++) {
    rE0[q] = W0[(long)(j0 + halfE*16 + q)*128 + hE];
    rEm[q] = Wm[(long)(j0 + halfE*16 + q)*128 + hE];
  }

  if (tid < 128) { sAt[tid] = coef[tid]; sB1[tid] = pb1[b*W_+tid]; sMB1[tid] = mb1[b*W_+tid]; }
  else if (tid < 160) { int j = tid-128; sB2[j] = pb2[b*D_+j0+j]; sMB2[j] = mb2[b*D_+j0+j]; }
  for (int i = tid; i < 129; i += 256) sBp[i] = coef[256+i];
  __syncthreads();

  for (int t = 0; t < SEG_; ++t) {
    int par = t & 1;
    float bp = sBp[t];
    float ca = (t>0) ? ETA_*sAt[t-1] : 0.f;

    float rq1k = 0.f, rq1km = 0.f;
    if (tid < 128) {
      rq1k  = q1k [((long)b*SEG_+t)*W_ + tid];
      rq1km = q1km[((long)b*SEG_+t)*W_ + tid];
      if (t > 0) {
        float mm = ETA_*sMB1[tid] - THETA_*sDZ[t-1][tid];
        sMB1[tid] = mm; sB1[tid] = PDEC_*sB1[tid] + mm;
      }
      if (tid < t) sGc[tid] = sAt[t-1-tid]*G[((long)b*SEG_+t)*SEG_ + tid];
    } else if (tid < 160) {
      int j = tid-128;
      if (t > 0) {
        float mm = ETA_*sMB2[j] - 2.f*THETA_*sEh[t-1][j];
        sMB2[j] = mm; sB2[j] = PDEC_*sB2[j] + mm;
      }
    }
    __syncthreads();

    if (tid < 128) {
      float acc = 0.f;
      for (int u = 0; u < t; ++u) acc = fmaf(sGc[u], sDZ[u][tid], acc);
      float z1 = bp*rq1k + ca*rq1km + sB1[tid] - THETA_*acc;
      sZ1[tid] = z1;
      sA1[t][tid] = z1 * sigf(z1);
    }
    __syncthreads();

    if (tid < t) {
      float acc = 0.f;
      #pragma unroll 8
      for (int h = 0; h < 128; ++h) acc = fmaf(sA1[tid][h], sA1[t][h], acc);
      sS[tid] = -2.f*THETA_*sAt[t-1-tid]*acc;
    }
    __syncthreads();

    {
      float g = 0.f, gm = 0.f;
      #pragma unroll
      for (int k = 0; k < 16; k++) {
        float a = sA1[t][lD + 8*k];
        g  = fmaf(rD0[k], a, g);
        gm = fmaf(rDm[k], a, gm);
      }
      float corr = 0.f;
      for (int u = lD; u < t; u += 8) corr = fmaf(sS[u], sEh[u][jD], corr);
      float tot = bp*g + ca*gm + corr;
      tot += __shfl_xor(tot,4); tot += __shfl_xor(tot,2); tot += __shfl_xor(tot,1);
      if (lD == 0) sEh[t][jD] = tot + sB2[jD] - Vm[((long)b*SEG_+t)*D_ + j0+jD];
    }
    __syncthreads();

    {
      float racc = 0.f;
      #pragma unroll
      for (int q = 0; q < 16; ++q) {
        float w = bp*rE0[q] + ca*rEm[q];
        racc = fmaf(w, sEh[t][halfE*16 + q], racc);
      }
      racc += __shfl_xor(racc,1);
      if (halfE == 0) gstore(&exR[(((long)par*B_ + b)*NB2_ + blk)*W_ + hE], racc);
      if (hE < t) {
        float eacc = 0.f;
        #pragma unroll
        for (int q = 0; q < 16; ++q)
          eacc = fmaf(sEh[hE][halfE*16 + q], sEh[t][halfE*16 + q], eacc);
        eacc += __shfl_xor(eacc,1);
        if (halfE == 0) gstore(&exEE[(((long)par*B_ + b)*NB2_ + blk)*W_ + hE], eacc);
      }
    }
    gbar(flags, blk, gbase + t + 1);

    {
      float racc = 0.f;
      #pragma unroll
      for (int k = 0; k < 16; ++k)
        racc += gload(&exR[(((long)par*B_ + b)*NB2_ + halfE*16 + k)*W_ + hE]);
      racc += __shfl_xor(racc,1);
      if (halfE == 0) sR[hE] = racc;
      if (hE < t) {
        float eacc = 0.f;
        #pragma unroll
        for (int k = 0; k < 16; ++k)
          eacc += gload(&exEE[(((long)par*B_ + b)*NB2_ + halfE*16 + k)*W_ + hE]);
        eacc += __shfl_xor(eacc,1);
        if (halfE == 0) sEEc[hE] = -2.f*THETA_*sAt[t-1-hE]*eacc;
      }
    }
    __syncthreads();
    if (tid < 128) {
      float macc = 0.f;
      for (int u = 0; u < t; ++u) macc = fmaf(sEEc[u], sA1[u][tid], macc);
      float z = sZ1[tid], sg = sigf(z);
      sDZ[t][tid] = 2.f*(sR[tid] + macc)*sg*(1.f + z*(1.f - sg));
    }
    __syncthreads();
  }

  // ---- epilogue ----
  if (tid < 128) {
    if (blk == 0) {
      float mm = ETA_*sMB1[tid] - THETA_*sDZ[127][tid];
      mb1[b*W_ + tid] = mm;
      pb1[b*W_ + tid] = PDEC_*sB1[tid] + mm;
    }
  } else if (tid < 160) {
    int j = tid-128;
    float mm = ETA_*sMB2[j] - 2.f*THETA_*sEh[127][j];
    mb2[b*D_ + j0+j] = mm;
    pb2[b*D_ + j0+j] = PDEC_*sB2[j] + mm;
  }
  for (int i = tid; i < 128*4; i += 256) {
    int t2 = i >> 2, hh = (i & 3) + blk*4;
    dz1o[((long)b*SEG_+t2)*W_ + hh] = sDZ[t2][hh];
    a1o [((long)b*SEG_+t2)*W_ + hh] = sA1[t2][hh];
  }
  for (int i = tid; i < 128*32; i += 256) {
    int t2 = i >> 5, jj = i & 31;
    eo[((long)b*SEG_+t2)*D_ + j0+jj] = sEh[t2][jj];
  }
}

// ---------------- weight/momentum reconstruction --------------------------
__global__ __launch_bounds__(256) void k_recon(
  float* __restrict__ pW1, float* __restrict__ mW1,
  float* __restrict__ pW2T, float* __restrict__ mW2T,
  const float* __restrict__ KMp, const float* __restrict__ Eh,
  const float* __restrict__ DZ1, const float* __restrict__ A1h,
  const float* __restrict__ coef)
{
  __shared__ float s1[16][33];
  __shared__ float s2[16][65];
  __shared__ float sCA[128], sCE[128];
  int dt = blockIdx.x, ht = blockIdx.y, kb = blockIdx.z;
  int kind = kb >> 1, b = kb & 1;
  int tid = threadIdx.x;
  int d0 = dt*32, hb = ht*64;
  const float* in1 = (kind ? Eh : KMp) + (long)b*SEG_*D_;
  const float* in2 = (kind ? A1h : DZ1) + (long)b*SEG_*W_;
  float* Pb = (kind ? pW2T : pW1) + (long)b*131072;
  float* Mb = (kind ? mW2T : mW1) + (long)b*131072;
  float f = kind ? -2.f*THETA_ : -THETA_;
  if (tid < 128) {
    sCA[tid] = f*coef[127 - tid];
    sCE[tid] = f*coef[128 + 127 - tid];
  }
  __syncthreads();
  int dd = tid >> 3, le = tid & 7;
  float accP[8] = {}, accM[8] = {};
  for (int u0 = 0; u0 < 128; u0 += 16) {
    for (int i = tid; i < 16*32; i += 256) {
      int uu = i >> 5, d2 = i & 31;
      s1[uu][d2] = in1[(long)(u0+uu)*D_ + d0 + d2];
    }
    for (int i = tid; i < 16*64; i += 256) {
      int uu = i >> 6, hl = i & 63;
      s2[uu][hl] = in2[(long)(u0+uu)*W_ + hb + hl];
    }
    __syncthreads();
    #pragma unroll
    for (int uu = 0; uu < 16; uu++) {
      float a = s1[uu][dd];
      float cAu = sCA[u0+uu], cEu = sCE[u0+uu];
      #pragma unroll
      for (int k = 0; k < 8; k++) {
        float v = a * s2[uu][k*8 + le];
        accP[k] = fmaf(cAu, v, accP[k]);
        accM[k] = fmaf(cEu, v, accM[k]);
      }
    }
    __syncthreads();
  }
  float b128 = coef[256 + 128];
  float eA   = ETA_*coef[127];
  float e128 = ETA_*coef[128 + 127];
  #pragma unroll
  for (int k = 0; k < 8; k++) {
    long idx = (long)(d0+dd)*W_ + hb + k*8 + le;
    float Po = Pb[idx], Mo = Mb[idx];
    Pb[idx] = b128*Po + eA*Mo + accP[k];
    Mb[idx] = e128*Mo + accM[k];
  }
}

// ---------------- host launcher ----------------
static inline void gemm(const float* A, const float* Bm, const float* bias, float* C,
                        int M, int N, int K, long sA, long sB, long sC, long sBias,
                        int batch, int bt, int silu_, hipStream_t st)
{
  dim3 g(N/64, (M+63)/64, batch), blk(256);
  if (!bt && !silu_) k_gemm<0,0><<<g,blk,0,st>>>(A,Bm,bias,C,M,N,K,sA,sB,sC,sBias);
  else if (!bt && silu_) k_gemm<0,1><<<g,blk,0,st>>>(A,Bm,bias,C,M,N,K,sA,sB,sC,sBias);
  else k_gemm<1,0><<<g,blk,0,st>>>(A,Bm,bias,C,M,N,K,sA,sB,sC,sBias);
}

extern "C" void kernel_launch(void* const* d_in, const int* in_sizes, int n_in,
                              void* d_out, int out_size, void* d_ws, size_t ws_size,
                              hipStream_t stream)
{
  (void)in_sizes; (void)n_in; (void)out_size; (void)ws_size;
  const int*   x     = (const int*)  d_in[0];
  const float* emb   = (const float*)d_in[1];
  const float* pers  = (const float*)d_in[2];
  const float* Wq    = (const float*)d_in[3];
  const float* bq    = (const float*)d_in[4];
  const float* Wk    = (const float*)d_in[5];
  const float* bk    = (const float*)d_in[6];
  const float* Wv    = (const float*)d_in[7];
  const float* bv    = (const float*)d_in[8];
  const float* aiw   = (const float*)d_in[9];
  const float* aib   = (const float*)d_in[10];
  const float* aow   = (const float*)d_in[11];
  const float* aob   = (const float*)d_in[12];
  const float* mW1in = (const float*)d_in[13];
  const float* mb1in = (const float*)d_in[14];
  const float* mW2in = (const float*)d_in[15];
  const float* mb2in = (const float*)d_in[16];
  const float* headw = (const float*)d_in[17];
  const float* headb = (const float*)d_in[18];
  float* out = (float*)d_out;
  float* ws  = (float*)d_ws;

  hipMemsetAsync(ws + MOM, 0, MOMSZ*sizeof(float), stream);
  hipMemsetAsync(ws + ZEROB, 0, 128*sizeof(float), stream);
  hipMemsetAsync(ws + CBAR, 0, (size_t)B_*NB2_*FSTR_*sizeof(int), stream);
  k_embed<<<dim3(B_*N_), dim3(256), 0, stream>>>(x, emb, ws+XEMB);
  k_init<<<dim3((2*PER_+255)/256), dim3(256), 0, stream>>>(
      mW1in, mb1in, mW2in, mb2in, ws+PW1, ws+PB1, ws+PW2T, ws+PB2);
  k_coef<<<dim3(1), dim3(64), 0, stream>>>(ws+COEF);

  for (int s = 0; s < NSEG_; s++) {
    const float* segA = ws + XEMB + (size_t)s*SEG_*D_;
    // Q-proj (MFMA, 64-row tiles), l2n
    k_mf<0,0,0,64><<<dim3(8, 2, B_), dim3(256), 0, stream>>>(
        segA, Wq, bq, ws+Q1, nullptr, SEG_, D_, D_, (long)N_*D_, 0, (long)SEG_*D_, 0, 0);
    k_l2n<<<dim3(B_*SEG_), dim3(256), 0, stream>>>(ws+Q1);
    // retrieve: AH = silu(Q1@W1+b1) [fp32 64²]; HBUF = AH@W2+b2 (MFMA BT, 64-row)
    gemm(ws+Q1, ws+PW1, ws+PB1, ws+AH, SEG_, W_, D_, (long)SEG_*D_, (long)D_*W_, (long)SEG_*W_, W_, B_, 0, 1, stream);
    k_mf<1,0,0,64><<<dim3(8, 2, B_), dim3(256), 0, stream>>>(
        ws+AH, ws+PW2T, ws+PB2, ws+HBUF, nullptr, SEG_, D_, W_,
        (long)SEG_*W_, (long)D_*W_, (long)SEG_*D_, D_, 0);
    // attention (concat fused into QKV GEMM)
    k_qkv_mfma<<<dim3(3*D_/128, (B_*T_+127)/128), dim3(256), 0, stream>>>(
        pers, ws+HBUF, ws+XEMB, s, aiw, aib, ws+QKV);
    k_attn<<<dim3(8, NH_, B_), dim3(256), 0, stream>>>(ws+QKV, ws+ATTN);
    k_mf<0,0,0,64><<<dim3(D_/128, 8, 1), dim3(256), 0, stream>>>(
        ws+ATTN, aow, aob, ws+SEGO, nullptr, B_*SEG_, D_, D_, 0, 0, 0, 0, 0);
    // fused K/V/Q projections of seg_out (MFMA, 64-row tiles), joint l2n
    k_gemmkvq_m<<<dim3(24, 4), dim3(256), 0, stream>>>(
        ws+SEGO, Wk, bk, Wv, bv, Wq, bq, ws+KM, ws+VM, ws+Q1);
    k_l2n2<<<dim3(2*B_*SEG_), dim3(256), 0, stream>>>(ws+KM, ws+Q1, B_*SEG_);
    // scan precompute: {Q1K, Q1Km} fused (fp32); G = K@K^T (fp32 64²)
    k_gemm2<<<dim3(2, 2, B_), dim3(256), 0, stream>>>(
        ws+KM, ws+PW1, ws+MW1, ws+AQ1K, ws+AQ1KM,
        D_, (long)SEG_*D_, (long)D_*W_, (long)SEG_*W_);
    gemm(ws+KM, ws+KM, ws+ZEROB, ws+AGRAM, SEG_, SEG_, D_,
         (long)SEG_*D_, (long)SEG_*D_, (long)SEG_*SEG_, 0, B_, 1, 0, stream);
    // the scan (round-10 structure)
    k_scan<<<dim3(NB2_, B_), dim3(256), 0, stream>>>(
        ws+PW2T, ws+MW2T, ws+PB1, ws+MB1, ws+PB2, ws+MB2, ws+VM,
        ws+AQ1K, ws+AQ1KM, ws+AGRAM,
        ws+ADZ1, ws+AA1H, ws+AEH,
        ws+AEXR, ws+AEXEE,
        ws+COEF, (int*)(ws+CBAR), s);
    // reconstruct weights/momenta
    k_recon<<<dim3(32, 2, 4), dim3(256), 0, stream>>>(
        ws+PW1, ws+MW1, ws+PW2T, ws+MW2T,
        ws+KM, ws+AEH, ws+ADZ1, ws+AA1H, ws+COEF);
    // mem_out = mlp(p_new, Q1); OUTS = SEGO * mem_out (fused MFMA epilogue, 64-row)
    gemm(ws+Q1, ws+PW1, ws+PB1, ws+AH, SEG_, W_, D_, (long)SEG_*D_, (long)D_*W_, (long)SEG_*W_, W_, B_, 0, 1, stream);
    k_mf<1,0,1,64><<<dim3(8, 2, B_), dim3(256), 0, stream>>>(
        ws+AH, ws+PW2T, ws+PB2, ws+OUTS + (size_t)s*SEG_*D_, ws+SEGO,
        SEG_, D_, W_, (long)SEG_*W_, (long)D_*W_, (long)N_*D_, D_, (long)SEG_*D_);
  }
  // head via bf16-split MFMA (128 tiles, 2000 blocks)
  k_head_mfma<<<dim3(V_/128, (B_*N_)/128), dim3(256), 0, stream>>>(
      ws+OUTS, headw, headb, out, B_*N_, V_, D_);
}